// Round 6
// baseline (1296.223 us; speedup 1.0000x reference)
//
#include <hip/hip_runtime.h>
#include <hip/hip_bf16.h>

typedef __hip_bfloat16 bf;
typedef __bf16 bf16x8 __attribute__((ext_vector_type(8)));
typedef float f32x4 __attribute__((ext_vector_type(4)));

#define DEVI __device__ __forceinline__

DEVI float b2f(bf v){ return __bfloat162float(v); }

// dual-path external load: f==0 -> fp32, f==1 -> bf16
DEVI float ldx(const void* p, size_t i, int f){
  return f ? __bfloat162float(((const bf*)p)[i]) : ((const float*)p)[i];
}

DEVI f32x4 mfma16(bf16x8 a, bf16x8 b, f32x4 c){
  return __builtin_amdgcn_mfma_f32_16x16x32_bf16(a, b, c, 0, 0, 0);
}

DEVI float gelu_t(float x){
  float u = 0.7978845608028654f * (x + 0.044715f * x * x * x);
  u = fminf(fmaxf(u, -30.f), 30.f);
  float e = __expf(2.f * u);
  return 0.5f * x * (1.f + (e - 1.f) / (e + 1.f));
}

// async global->LDS, 16B per lane, wave-uniform LDS base (HW adds lane*16)
DEVI void gload16(const bf* g, char* l){
  __builtin_amdgcn_global_load_lds((const __attribute__((address_space(1))) void*)g,
                                   (__attribute__((address_space(3))) void*)l, 16, 0, 0);
}

// ------------------------------------------------------------------
// dtype detect: norm1_s == ones. fp32 word = 0x3F800000; bf16 pair = 0x3F803F80.
__global__ void detect_dtype(const void* n1s, int* flag){
  unsigned u = *(const unsigned*)n1s;
  *flag = (u == 0x3F800000u) ? 0 : 1;
}

// convert external array -> bf16 buffer (dual path)
__global__ __launch_bounds__(256) void conv_bf16(const void* src, bf* dst, int n, const int* flag){
  int f = *flag;
  int i = blockIdx.x * 256 + threadIdx.x;
  if (i < n) dst[i] = f ? ((const bf*)src)[i] : __float2bfloat16(((const float*)src)[i]);
}

// ------------------------------------------------------------------
// transpose+convert: Wt[n][k] = bf16(W[k][n])   (K, N multiples of 32)
__global__ __launch_bounds__(256) void transpose_w(const void* __restrict__ W, bf* __restrict__ Wt,
                                                   int K, int N, const int* flag){
  __shared__ bf tile[32][33];
  const int f = *flag;
  int n0 = blockIdx.x * 32, k0 = blockIdx.y * 32;
  int tx = threadIdx.x & 31, ty = threadIdx.x >> 5;
  #pragma unroll
  for (int i = ty; i < 32; i += 8)
    tile[i][tx] = __float2bfloat16(ldx(W, (size_t)(k0 + i) * N + n0 + tx, f));
  __syncthreads();
  #pragma unroll
  for (int i = ty; i < 32; i += 8) Wt[(size_t)(n0 + i) * K + k0 + tx] = tile[tx][i];
}

// ------------------------------------------------------------------
DEVI void blockreduce2(float& s, float& s2){
  #pragma unroll
  for (int off = 32; off > 0; off >>= 1){
    s  += __shfl_down(s, off);
    s2 += __shfl_down(s2, off);
  }
  __shared__ float sh[8];
  int wv = threadIdx.x >> 6;
  if ((threadIdx.x & 63) == 0){ sh[wv*2] = s; sh[wv*2+1] = s2; }
  __syncthreads();
  s  = sh[0] + sh[2] + sh[4] + sh[6];
  s2 = sh[1] + sh[3] + sh[5] + sh[7];
}

// LN1 fused with window gather for ONE batch (25 windows, 4925 rows local).
// Pads (gh>=64 || gw>=64) are exact zeros (pad applied AFTER layernorm in ref).
__global__ __launch_bounds__(256) void ln_window(const void* __restrict__ x, const void* __restrict__ cls,
    const bf* __restrict__ g, const bf* __restrict__ bb, bf* __restrict__ winx, int batch,
    const int* flag){
  const int f = *flag;
  int row = blockIdx.x;                 // 0..4924 (local)
  int wid = row / 197, p = row % 197;   // wid 0..24
  int wi = wid / 5, wj = wid % 5;
  bf* dst = winx + (size_t)row * 768;
  int tid = threadIdx.x;
  const void* src = nullptr;
  size_t base = 0;
  if (p == 0){ src = cls; base = (size_t)batch * 768; }
  else {
    int pi = (p - 1) / 14, pj = (p - 1) % 14;
    int gh = wi * 14 + pi, gw = wj * 14 + pj;
    if (gh < 64 && gw < 64){ src = x; base = ((size_t)((batch * 64 + gh) * 64 + gw)) * 768; }
  }
  if (!src){
    for (int c = tid; c < 768; c += 256) dst[c] = __float2bfloat16(0.f);
    return;
  }
  float v[3]; float s = 0.f, s2 = 0.f;
  #pragma unroll
  for (int k = 0; k < 3; k++){ v[k] = ldx(src, base + tid + k*256, f); s += v[k]; s2 += v[k]*v[k]; }
  blockreduce2(s, s2);
  float mu  = s  * (1.f/768.f);
  float var = fmaxf(s2 * (1.f/768.f) - mu*mu, 0.f);
  float rs  = rsqrtf(var + 1e-6f);
  #pragma unroll
  for (int k = 0; k < 3; k++){
    int c = tid + k*256;
    dst[c] = __float2bfloat16((v[k]-mu)*rs*b2f(g[c]) + b2f(bb[c]));
  }
}

// LN over fp32 rows -> bf16
__global__ __launch_bounds__(256) void ln_f32(const float* __restrict__ in, const bf* __restrict__ g,
    const bf* __restrict__ bb, bf* __restrict__ outb){
  size_t row = blockIdx.x;
  const float* src = in + row * 768;
  bf* dst = outb + row * 768;
  int tid = threadIdx.x;
  float v[3]; float s = 0.f, s2 = 0.f;
  #pragma unroll
  for (int k = 0; k < 3; k++){ v[k] = src[tid + k*256]; s += v[k]; s2 += v[k]*v[k]; }
  blockreduce2(s, s2);
  float mu  = s  * (1.f/768.f);
  float var = fmaxf(s2 * (1.f/768.f) - mu*mu, 0.f);
  float rs  = rsqrtf(var + 1e-6f);
  #pragma unroll
  for (int k = 0; k < 3; k++){
    int c = tid + k*256;
    dst[c] = __float2bfloat16((v[k]-mu)*rs*b2f(g[c]) + b2f(bb[c]));
  }
}

// ------------------------------------------------------------------
// GEMM: out[M,N] = act(A[M,K] @ Bt[N,K]^T + bias) (+res)
// 128x128 tile, BK=32, 4 waves, mfma 16x16x32 bf16.
// global_load_lds w16 staging + XCD-chunked bijective block swizzle.
// flags: 1=gelu, 2=+res(fp32), 4=external out (dtype per *dflag), row_off for flag&4.
// NOTE: last m-tile overreads A rows >= M (stays in mapped ws; garbage only
// lands in acc rows that are masked on store).
__global__ __launch_bounds__(256) void gemm128(const bf* __restrict__ A, const bf* __restrict__ Bt,
    const bf* __restrict__ bias, const float* __restrict__ res, void* __restrict__ out,
    int M, int N, int K, int flags, const int* dflag, int row_off)
{
  __shared__ __bf16 sA[128*32];
  __shared__ __bf16 sB[128*32];
  const int df = *dflag;
  // ---- XCD-chunked bijective swizzle (8 XCDs): each XCD owns a contiguous
  // range of logical tiles; logical order has n fastest so neighbors share A-panels.
  const int gx = gridDim.x;
  const int nwg = gx * gridDim.y;
  const int lin = blockIdx.y * gx + blockIdx.x;
  const int q = nwg >> 3, r = nwg & 7;
  const int xcd = lin & 7, pos = lin >> 3;
  const int logical = (xcd < r ? xcd * (q + 1) : r * (q + 1) + (xcd - r) * q) + pos;
  const int m0 = (logical / gx) * 128, n0 = (logical % gx) * 128;

  const int tid = threadIdx.x, wv = tid >> 6, l = tid & 63;
  const int wm = (wv >> 1) * 64, wn = (wv & 1) * 64;
  const int li = l & 15, lk = l >> 4;
  f32x4 acc[4][4];
  #pragma unroll
  for (int i = 0; i < 4; i++)
    #pragma unroll
    for (int j = 0; j < 4; j++){ f32x4 z = {0.f,0.f,0.f,0.f}; acc[i][j] = z; }

  // staging addresses: instr i of wave wv covers tile rows [wv*32+16i, +16)
  const int l4 = l >> 2, lc = (l & 3) * 8;
  const int ra0 = wv * 32 + l4;
  const int ra1 = ra0 + 16;
  const bf* gA0 = A  + (size_t)(m0 + ra0) * K + lc;
  const bf* gA1 = A  + (size_t)(m0 + ra1) * K + lc;
  const bf* gB0 = Bt + (size_t)(n0 + ra0) * K + lc;
  const bf* gB1 = Bt + (size_t)(n0 + ra1) * K + lc;
  char* sAb0 = (char*)sA + wv * 2048;
  char* sAb1 = sAb0 + 1024;
  char* sBb0 = (char*)sB + wv * 2048;
  char* sBb1 = sBb0 + 1024;

  for (int k0 = 0; k0 < K; k0 += 32){
    __syncthreads();                    // previous compute done before overwrite
    gload16(gA0 + k0, sAb0);
    gload16(gA1 + k0, sAb1);
    gload16(gB0 + k0, sBb0);
    gload16(gB1 + k0, sBb1);
    __syncthreads();                    // vmcnt drained at barrier -> data ready
    bf16x8 af[4], bfr[4];
    #pragma unroll
    for (int i = 0; i < 4; i++) af[i]  = *(const bf16x8*)&sA[(wm + i*16 + li)*32 + lk*8];
    #pragma unroll
    for (int j = 0; j < 4; j++) bfr[j] = *(const bf16x8*)&sB[(wn + j*16 + li)*32 + lk*8];
    #pragma unroll
    for (int i = 0; i < 4; i++)
      #pragma unroll
      for (int j = 0; j < 4; j++) acc[i][j] = mfma16(af[i], bfr[j], acc[i][j]);
  }
  #pragma unroll
  for (int i = 0; i < 4; i++){
    #pragma unroll
    for (int j = 0; j < 4; j++){
      int colg = n0 + wn + j*16 + li;
      float bc = b2f(bias[colg]);
      #pragma unroll
      for (int r2 = 0; r2 < 4; r2++){
        int rowg = m0 + wm + i*16 + lk*4 + r2;
        if (rowg < M){
          float vv = acc[i][j][r2] + bc;
          if (flags & 1) vv = gelu_t(vv);
          if (flags & 2) vv += res[(size_t)rowg * N + colg];
          if (flags & 4){
            size_t oidx = (size_t)(row_off + rowg) * N + colg;
            if (df == 0) ((float*)out)[oidx] = vv;
            else         ((bf*)out)[oidx]    = __float2bfloat16(vv);
          } else {
            ((bf*)out)[(size_t)rowg * N + colg] = __float2bfloat16(vv);
          }
        }
      }
    }
  }
}

// ------------------------------------------------------------------
// Relative-position bias tables per (window-local, head) via MFMA. 300 blocks/batch.
// relH[qi=(pi*14+pj)][kh] = q_vec . rel_pos_h[pi-kh+13]; relW analogous. Unscaled q.
__global__ __launch_bounds__(256) void bias_tables(const bf* __restrict__ qkv,
    const bf* __restrict__ rph, const bf* __restrict__ rpw,
    bf* __restrict__ relHg, bf* __restrict__ relWg){
  const int blk = blockIdx.x;              // w*12 + h, w local 0..24
  const int w = blk / 12, h = blk % 12;
  const int tid = threadIdx.x, wv = tid >> 6, l = tid & 63;
  const int li = l & 15, lk = l >> 4;
  const bf* qbase = qkv + (size_t)w * 197 * 2304 + h * 64;
  const size_t obase = (size_t)blk * 196 * 14;
  for (int g = wv; g < 28; g += 4){
    bool isH = (g < 14);
    int pfix = isH ? g : (g - 14);         // pi for H, pj for W
    int var  = li < 13 ? li : 13;          // pj for H, pi for W (clamped dup lanes 14,15)
    int q = isH ? (1 + pfix*14 + var) : (1 + var*14 + pfix);
    f32x4 acc = {0.f,0.f,0.f,0.f};
    const bf* rp = isH ? rph : rpw;
    #pragma unroll
    for (int s = 0; s < 2; s++){
      bf16x8 a = *(const bf16x8*)(qbase + (size_t)q * 2304 + s*32 + lk*8);
      int idx = pfix + 13 - li;
      if (idx < 0) idx = 0;
      bf16x8 b = *(const bf16x8*)(rp + idx * 64 + s*32 + lk*8);
      acc = mfma16(a, b, acc);
    }
    #pragma unroll
    for (int r = 0; r < 4; r++){
      int mrow = lk*4 + r;                 // pj for H, pi for W
      int col = li;                        // kh / kw
      if (mrow <= 13 && col <= 13){
        int qi = isH ? (pfix*14 + mrow) : (mrow*14 + pfix);
        bf* dst = isH ? relHg : relWg;
        dst[obase + (size_t)qi * 14 + col] = __float2bfloat16(acc[r]);
      }
    }
  }
}

// ------------------------------------------------------------------
// Attention per (window-local, head). 300 blocks/batch, 4 waves.
__global__ __launch_bounds__(256) void attn_win(const bf* __restrict__ qkv,
    const bf* __restrict__ relHg, const bf* __restrict__ relWg, bf* __restrict__ aout){
  __shared__ __bf16 Vt[64][232];     // V transposed [c][key], keys 0..223 (pad zero)
  __shared__ __bf16 Pl[4][16][232];  // per-wave P tile [qrow][key]
  const int blk = blockIdx.x;
  const int w = blk / 12, h = blk % 12;
  const int tid = threadIdx.x, wv = tid >> 6, l = tid & 63;
  const int li = l & 15, lk = l >> 4;
  const bf* qp = qkv + (size_t)w * 197 * 2304 + h * 64;
  const bf* kp = qp + 768;
  const bf* vp = qp + 1536;
  {
    const int cc = (tid & 7) * 8, rb = tid >> 3;
    #pragma unroll
    for (int pass = 0; pass < 7; pass++){
      int r = pass * 32 + rb;              // 0..223
      __bf16 vvv[8];
      if (r < 197){
        bf16x8 t = *(const bf16x8*)(vp + (size_t)r * 2304 + cc);
        #pragma unroll
        for (int e = 0; e < 8; e++) vvv[e] = t[e];
      } else {
        #pragma unroll
        for (int e = 0; e < 8; e++) vvv[e] = (__bf16)0.f;
      }
      #pragma unroll
      for (int e = 0; e < 8; e++) Vt[cc + e][r] = vvv[e];
    }
  }
  for (int i = l; i < 256; i += 64) Pl[wv][i >> 4][208 + (i & 15)] = (__bf16)0.f;
  __syncthreads();
  const bf* rHb = relHg + (size_t)blk * 196 * 14;
  const bf* rWb = relWg + (size_t)blk * 196 * 14;
  for (int qt = wv; qt < 13; qt += 4){
    int qrow = qt * 16 + li; if (qrow > 196) qrow = 196;
    bf16x8 qa0 = *(const bf16x8*)(qp + (size_t)qrow * 2304 + lk*8);
    bf16x8 qa1 = *(const bf16x8*)(qp + (size_t)qrow * 2304 + 32 + lk*8);
    f32x4 sc[13];
    #pragma unroll
    for (int ct = 0; ct < 13; ct++){
      int kr = ct * 16 + li; if (kr > 196) kr = 196;
      bf16x8 kb0 = *(const bf16x8*)(kp + (size_t)kr * 2304 + lk*8);
      bf16x8 kb1 = *(const bf16x8*)(kp + (size_t)kr * 2304 + 32 + lk*8);
      f32x4 z = {0.f,0.f,0.f,0.f};
      z = mfma16(qa0, kb0, z);
      z = mfma16(qa1, kb1, z);
      sc[ct] = z;
    }
    float mx[4] = {-3e38f, -3e38f, -3e38f, -3e38f};
    #pragma unroll
    for (int ct = 0; ct < 13; ct++){
      #pragma unroll
      for (int r = 0; r < 4; r++){
        int col = ct * 16 + li;
        int grow = qt * 16 + lk*4 + r;
        float s = sc[ct][r] * 0.125f;      // SCALE = HD^-0.5
        if (col >= 197) s = -1e30f;
        else if (col >= 1 && grow >= 1 && grow < 197){
          int qi = grow - 1, ki = col - 1;
          int kh = ki / 14, kw = ki - kh * 14;
          s += b2f(rHb[qi*14 + kh]) + b2f(rWb[qi*14 + kw]);
        }
        sc[ct][r] = s;
        mx[r] = fmaxf(mx[r], s);
      }
    }
    #pragma unroll
    for (int r = 0; r < 4; r++){
      #pragma unroll
      for (int off = 1; off < 16; off <<= 1) mx[r] = fmaxf(mx[r], __shfl_xor(mx[r], off));
    }
    float den[4] = {0.f,0.f,0.f,0.f};
    #pragma unroll
    for (int ct = 0; ct < 13; ct++)
      #pragma unroll
      for (int r = 0; r < 4; r++){
        float e = __expf(sc[ct][r] - mx[r]);
        sc[ct][r] = e; den[r] += e;
      }
    #pragma unroll
    for (int r = 0; r < 4; r++){
      #pragma unroll
      for (int off = 1; off < 16; off <<= 1) den[r] += __shfl_xor(den[r], off);
      den[r] = 1.f / den[r];
    }
    #pragma unroll
    for (int ct = 0; ct < 13; ct++)
      #pragma unroll
      for (int r = 0; r < 4; r++)
        Pl[wv][lk*4 + r][ct*16 + li] = (__bf16)(sc[ct][r] * den[r]);
    asm volatile("s_waitcnt lgkmcnt(0)" ::: "memory");
    __builtin_amdgcn_sched_barrier(0);
    #pragma unroll
    for (int n = 0; n < 4; n++){
      f32x4 o = {0.f,0.f,0.f,0.f};
      #pragma unroll
      for (int ks = 0; ks < 7; ks++){
        bf16x8 pa = *(const bf16x8*)&Pl[wv][li][ks*32 + lk*8];
        bf16x8 vb = *(const bf16x8*)&Vt[n*16 + li][ks*32 + lk*8];
        o = mfma16(pa, vb, o);
      }
      #pragma unroll
      for (int r = 0; r < 4; r++){
        int grow = qt * 16 + lk*4 + r;
        if (grow < 197)
          aout[((size_t)w * 197 + grow) * 768 + h*64 + n*16 + li] = __float2bfloat16(o[r]);
      }
    }
  }
}

// ------------------------------------------------------------------
// Un-window + cls-mean + residual for ONE batch -> tok2 rows of that batch (fp32).
__global__ __launch_bounds__(256) void unwindow(const void* __restrict__ x, const void* __restrict__ cls,
    const bf* __restrict__ projo, float* __restrict__ tok2, int batch, const int* flag){
  const int f = *flag;
  int t = blockIdx.x;                  // 0..4096 local token
  for (int c = threadIdx.x; c < 768; c += 256){
    float val, add;
    if (t == 0){
      val = ldx(cls, (size_t)batch * 768 + c, f);
      float s = 0.f;
      #pragma unroll
      for (int wi = 0; wi < 25; wi++)
        s += b2f(projo[((size_t)wi * 197) * 768 + c]);
      add = s * 0.04f;                  // 1/25
    } else {
      int idx = t - 1, gh = idx >> 6, gw = idx & 63;
      int wi = gh / 14, pi = gh % 14, wj = gw / 14, pj = gw % 14;
      int wwin = wi*5 + wj, tl = 1 + pi*14 + pj;
      val = ldx(x, ((size_t)batch * 4096 + idx) * 768 + c, f);
      add = b2f(projo[((size_t)wwin * 197 + tl) * 768 + c]);
    }
    tok2[((size_t)batch * 4097 + t) * 768 + c] = val + add;
  }
}

// ------------------------------------------------------------------
// Workspace layout — peak 105,637,248 B (~100.7 MiB). All boundaries exact:
//   [0,256)                   dtype flag
//   [256, 14,156,032)         transposed bf16 weights
//   [14,156,032, 14,182,912)  converted small arrays
//   [14,188,800, 17,481,600)  relH/relW per batch     } MLP-phase reuse:
//   [17,481,600, 25,046,400)  winx_b / attn_ob        }  hbuf  [14,188,800, 20,481,792)
//   [25,046,400, 47,740,800)  qkvB                    }  fc1g  [20,482,048, 45,654,016)
//   [47,740,800, 55,305,600)  projo_b                 }  (no overlap with hbuf/tok2)
//   [55,305,600, 105,637,248) tok2 fp32 (live through MLP)
extern "C" void kernel_launch(void* const* d_in, const int* in_sizes, int n_in,
                              void* d_out, int out_size, void* d_ws, size_t ws_size,
                              hipStream_t stream){
  (void)in_sizes; (void)n_in; (void)out_size; (void)ws_size;
  const void* x      = d_in[0];
  const void* cls    = d_in[1];
  const void* qkv_w  = d_in[2];
  const void* qkv_bv = d_in[3];
  const void* proj_w = d_in[4];
  const void* proj_bv= d_in[5];
  const void* rph    = d_in[6];
  const void* rpw    = d_in[7];
  const void* n1s    = d_in[8];
  const void* n1b    = d_in[9];
  const void* n2s    = d_in[10];
  const void* n2b    = d_in[11];
  const void* fc1_w  = d_in[12];
  const void* fc1_bv = d_in[13];
  const void* fc2_w  = d_in[14];
  const void* fc2_bv = d_in[15];

  char* ws = (char*)d_ws;
  int* flagp  = (int*)(ws + 0);
  bf* wt_qkv  = (bf*)(ws + 256);
  bf* wt_proj = (bf*)(ws + 3539200);
  bf* wt_fc1  = (bf*)(ws + 4718848);
  bf* wt_fc2  = (bf*)(ws + 9437440);
  bf* c_qkv_b = (bf*)(ws + 14156032);   // 2304
  bf* c_proj_b= (bf*)(ws + 14160640);   // 768
  bf* c_fc1_b = (bf*)(ws + 14162176);   // 3072
  bf* c_fc2_b = (bf*)(ws + 14168320);   // 768
  bf* c_n1s   = (bf*)(ws + 14169856);   // 768
  bf* c_n1b   = (bf*)(ws + 14171392);   // 768
  bf* c_n2s   = (bf*)(ws + 14172928);   // 768
  bf* c_n2b   = (bf*)(ws + 14174464);   // 768
  bf* c_rph   = (bf*)(ws + 14176000);   // 1728
  bf* c_rpw   = (bf*)(ws + 14179456);   // 1728
  bf* relH_b  = (bf*)(ws + 14188800);   // 25*12*196*14
  bf* relW_b  = relH_b + 823200;
  bf* winx_b  = (bf*)(ws + 17481600);   // 4925x768
  bf* attn_ob = winx_b;                  // reuse
  bf* qkvB    = (bf*)(ws + 25046400);   // 4925x2304
  bf* projo_b = (bf*)(ws + 47740800);   // 4925x768
  float* tok2 = (float*)(ws + 55305600);// 16388x768 fp32
  bf* hbuf    = (bf*)(ws + 14188800);   // 4097x768 chunk (MLP phase), ends 20,481,792
  bf* fc1g    = (bf*)(ws + 20482048);   // 4097x3072 chunk, ends 45,654,016

  detect_dtype<<<1, 1, 0, stream>>>(n1s, flagp);

  conv_bf16<<<9,  256, 0, stream>>>(qkv_bv,  c_qkv_b, 2304, flagp);
  conv_bf16<<<3,  256, 0, stream>>>(proj_bv, c_proj_b, 768, flagp);
  conv_bf16<<<12, 256, 0, stream>>>(fc1_bv,  c_fc1_b, 3072, flagp);
  conv_bf16<<<3,  256, 0, stream>>>(fc2_bv,  c_fc2_b,  768, flagp);
  conv_bf16<<<3,  256, 0, stream>>>(n1s, c_n1s, 768, flagp);
  conv_bf16<<<3,  256, 0, stream>>>(n1b, c_n1b, 768, flagp);
  conv_bf16<<<3,  256, 0, stream>>>(n2s, c_n2s, 768, flagp);
  conv_bf16<<<3,  256, 0, stream>>>(n2b, c_n2b, 768, flagp);
  conv_bf16<<<7,  256, 0, stream>>>(rph, c_rph, 1728, flagp);
  conv_bf16<<<7,  256, 0, stream>>>(rpw, c_rpw, 1728, flagp);

  transpose_w<<<dim3(72, 24), 256, 0, stream>>>(qkv_w, wt_qkv, 768, 2304, flagp);
  transpose_w<<<dim3(24, 24), 256, 0, stream>>>(proj_w, wt_proj, 768, 768, flagp);
  transpose_w<<<dim3(96, 24), 256, 0, stream>>>(fc1_w, wt_fc1, 768, 3072, flagp);
  transpose_w<<<dim3(24, 96), 256, 0, stream>>>(fc2_w, wt_fc2, 3072, 768, flagp);

  for (int b = 0; b < 4; b++){
    ln_window<<<4925, 256, 0, stream>>>(x, cls, c_n1s, c_n1b, winx_b, b, flagp);
    gemm128<<<dim3(18, 39), 256, 0, stream>>>(winx_b, wt_qkv, c_qkv_b, nullptr, qkvB,
                                              4925, 2304, 768, 0, flagp, 0);
    bias_tables<<<300, 256, 0, stream>>>(qkvB, c_rph, c_rpw, relH_b, relW_b);
    attn_win<<<300, 256, 0, stream>>>(qkvB, relH_b, relW_b, attn_ob);
    gemm128<<<dim3(6, 39), 256, 0, stream>>>(attn_ob, wt_proj, c_proj_b, nullptr, projo_b,
                                             4925, 768, 768, 0, flagp, 0);
    unwindow<<<4097, 256, 0, stream>>>(x, cls, projo_b, tok2, b, flagp);
  }

  for (int c = 0; c < 4; c++){
    ln_f32<<<4097, 256, 0, stream>>>(tok2 + (size_t)c * 4097 * 768, c_n2s, c_n2b, hbuf);
    gemm128<<<dim3(24, 33), 256, 0, stream>>>(hbuf, wt_fc1, c_fc1_b, nullptr, fc1g,
                                              4097, 3072, 768, 1, flagp, 0);
    gemm128<<<dim3(6, 33), 256, 0, stream>>>(fc1g, wt_fc2, c_fc2_b,
                                             tok2 + (size_t)c * 4097 * 768,
                                             d_out,
                                             4097, 768, 3072, 2 | 4, flagp, c * 4097);
  }
}

// Round 7
// 1057.748 us; speedup vs baseline: 1.2255x; 1.2255x over previous
//
#include <hip/hip_runtime.h>
#include <hip/hip_bf16.h>

typedef __hip_bfloat16 bf;
typedef __bf16 bf16x8 __attribute__((ext_vector_type(8)));
typedef float f32x4 __attribute__((ext_vector_type(4)));

#define DEVI __device__ __forceinline__

DEVI float b2f(bf v){ return __bfloat162float(v); }

// dual-path external load: f==0 -> fp32, f==1 -> bf16
DEVI float ldx(const void* p, size_t i, int f){
  return f ? __bfloat162float(((const bf*)p)[i]) : ((const float*)p)[i];
}

DEVI f32x4 mfma16(bf16x8 a, bf16x8 b, f32x4 c){
  return __builtin_amdgcn_mfma_f32_16x16x32_bf16(a, b, c, 0, 0, 0);
}

DEVI float gelu_t(float x){
  float u = 0.7978845608028654f * (x + 0.044715f * x * x * x);
  u = fminf(fmaxf(u, -30.f), 30.f);
  float e = __expf(2.f * u);
  return 0.5f * x * (1.f + (e - 1.f) / (e + 1.f));
}

// async global->LDS, 16B per lane, wave-uniform LDS base (HW adds lane*16)
DEVI void gload16(const bf* g, char* l){
  __builtin_amdgcn_global_load_lds((const __attribute__((address_space(1))) void*)g,
                                   (__attribute__((address_space(3))) void*)l, 16, 0, 0);
}

// ------------------------------------------------------------------
// dtype detect: norm1_s == ones. fp32 word = 0x3F800000; bf16 pair = 0x3F803F80.
__global__ void detect_dtype(const void* n1s, int* flag){
  unsigned u = *(const unsigned*)n1s;
  *flag = (u == 0x3F800000u) ? 0 : 1;
}

// convert external array -> bf16 buffer (dual path)
__global__ __launch_bounds__(256) void conv_bf16(const void* src, bf* dst, int n, const int* flag){
  int f = *flag;
  int i = blockIdx.x * 256 + threadIdx.x;
  if (i < n) dst[i] = f ? ((const bf*)src)[i] : __float2bfloat16(((const float*)src)[i]);
}

// ------------------------------------------------------------------
// transpose+convert: Wt[n][k] = bf16(W[k][n])   (K, N multiples of 32)
__global__ __launch_bounds__(256) void transpose_w(const void* __restrict__ W, bf* __restrict__ Wt,
                                                   int K, int N, const int* flag){
  __shared__ bf tile[32][33];
  const int f = *flag;
  int n0 = blockIdx.x * 32, k0 = blockIdx.y * 32;
  int tx = threadIdx.x & 31, ty = threadIdx.x >> 5;
  #pragma unroll
  for (int i = ty; i < 32; i += 8)
    tile[i][tx] = __float2bfloat16(ldx(W, (size_t)(k0 + i) * N + n0 + tx, f));
  __syncthreads();
  #pragma unroll
  for (int i = ty; i < 32; i += 8) Wt[(size_t)(n0 + i) * K + k0 + tx] = tile[tx][i];
}

// ------------------------------------------------------------------
DEVI void blockreduce2(float& s, float& s2){
  #pragma unroll
  for (int off = 32; off > 0; off >>= 1){
    s  += __shfl_down(s, off);
    s2 += __shfl_down(s2, off);
  }
  __shared__ float sh[8];
  int wv = threadIdx.x >> 6;
  if ((threadIdx.x & 63) == 0){ sh[wv*2] = s; sh[wv*2+1] = s2; }
  __syncthreads();
  s  = sh[0] + sh[2] + sh[4] + sh[6];
  s2 = sh[1] + sh[3] + sh[5] + sh[7];
}

// LN1 fused with window gather for ONE batch (25 windows, 4925 rows local).
__global__ __launch_bounds__(256) void ln_window(const void* __restrict__ x, const void* __restrict__ cls,
    const bf* __restrict__ g, const bf* __restrict__ bb, bf* __restrict__ winx, int batch,
    const int* flag){
  const int f = *flag;
  int row = blockIdx.x;                 // 0..4924 (local)
  int wid = row / 197, p = row % 197;   // wid 0..24
  int wi = wid / 5, wj = wid % 5;
  bf* dst = winx + (size_t)row * 768;
  int tid = threadIdx.x;
  const void* src = nullptr;
  size_t base = 0;
  if (p == 0){ src = cls; base = (size_t)batch * 768; }
  else {
    int pi = (p - 1) / 14, pj = (p - 1) % 14;
    int gh = wi * 14 + pi, gw = wj * 14 + pj;
    if (gh < 64 && gw < 64){ src = x; base = ((size_t)((batch * 64 + gh) * 64 + gw)) * 768; }
  }
  if (!src){
    for (int c = tid; c < 768; c += 256) dst[c] = __float2bfloat16(0.f);
    return;
  }
  float v[3]; float s = 0.f, s2 = 0.f;
  #pragma unroll
  for (int k = 0; k < 3; k++){ v[k] = ldx(src, base + tid + k*256, f); s += v[k]; s2 += v[k]*v[k]; }
  blockreduce2(s, s2);
  float mu  = s  * (1.f/768.f);
  float var = fmaxf(s2 * (1.f/768.f) - mu*mu, 0.f);
  float rs  = rsqrtf(var + 1e-6f);
  #pragma unroll
  for (int k = 0; k < 3; k++){
    int c = tid + k*256;
    dst[c] = __float2bfloat16((v[k]-mu)*rs*b2f(g[c]) + b2f(bb[c]));
  }
}

// LN over fp32 rows -> bf16
__global__ __launch_bounds__(256) void ln_f32(const float* __restrict__ in, const bf* __restrict__ g,
    const bf* __restrict__ bb, bf* __restrict__ outb){
  size_t row = blockIdx.x;
  const float* src = in + row * 768;
  bf* dst = outb + row * 768;
  int tid = threadIdx.x;
  float v[3]; float s = 0.f, s2 = 0.f;
  #pragma unroll
  for (int k = 0; k < 3; k++){ v[k] = src[tid + k*256]; s += v[k]; s2 += v[k]*v[k]; }
  blockreduce2(s, s2);
  float mu  = s  * (1.f/768.f);
  float var = fmaxf(s2 * (1.f/768.f) - mu*mu, 0.f);
  float rs  = rsqrtf(var + 1e-6f);
  #pragma unroll
  for (int k = 0; k < 3; k++){
    int c = tid + k*256;
    dst[c] = __float2bfloat16((v[k]-mu)*rs*b2f(g[c]) + b2f(bb[c]));
  }
}

// ------------------------------------------------------------------
// GEMM: out[M,N] = act(A[M,K] @ Bt[N,K]^T + bias) (+res)
// 128x128 tile, BK=64, 8 waves (512 thr), double-buffered LDS w/ 2-phase
// pipeline (stage k+1 before compute k), st-8x16B XOR swizzle (T2) applied
// via pre-swizzled global source + swizzled ds_read. XCD-chunked swizzle (T1).
// K must be a multiple of 64. N multiple of 128. A rows may overread past M
// (must stay in mapped memory; garbage rows are masked at store).
// flags: 1=gelu, 2=+res(fp32), 4=external out (dtype per *dflag), row_off for flag&4.
__global__ __launch_bounds__(512) void gemm128(const bf* __restrict__ A, const bf* __restrict__ Bt,
    const bf* __restrict__ bias, const float* __restrict__ res, void* __restrict__ out,
    int M, int N, int K, int flags, const int* dflag, int row_off)
{
  __shared__ __bf16 sA[2][128*64];
  __shared__ __bf16 sB[2][128*64];
  const int df = *dflag;
  // ---- XCD-chunked bijective swizzle (8 XCDs), n fastest in logical order
  const int gx = gridDim.x;
  const int nwg = gx * gridDim.y;
  const int lin = blockIdx.y * gx + blockIdx.x;
  const int q = nwg >> 3, r = nwg & 7;
  const int xcd = lin & 7, pos = lin >> 3;
  const int logical = (xcd < r ? xcd * (q + 1) : r * (q + 1) + (xcd - r) * q) + pos;
  const int m0 = (logical / gx) * 128, n0 = (logical % gx) * 128;

  const int tid = threadIdx.x, wv = tid >> 6, l = tid & 63;
  const int wm = (wv >> 2) * 64;        // 2 row groups of 64
  const int wn = (wv & 3) * 32;         // 4 col groups of 32
  const int li = l & 15, lk = l >> 4;
  const int xr = li & 7;                // row&7 for frag reads

  f32x4 acc[4][2];
  #pragma unroll
  for (int i = 0; i < 4; i++)
    #pragma unroll
    for (int j = 0; j < 2; j++){ f32x4 z = {0.f,0.f,0.f,0.f}; acc[i][j] = z; }

  // ---- staging addresses (pre-swizzled global source, linear LDS dest)
  // instr covers 8KB: rows [i*64, i*64+64), thread t -> row i*64 + (t>>3), slot t&7.
  const int rA = tid >> 3;                       // 0..63
  const int sl = (tid & 7) ^ (rA & 7);           // swizzled source slot
  const bf* gA0 = A  + (size_t)(m0 + rA)      * K + sl * 8;
  const bf* gA1 = A  + (size_t)(m0 + 64 + rA) * K + sl * 8;
  const bf* gB0 = Bt + (size_t)(n0 + rA)      * K + sl * 8;
  const bf* gB1 = Bt + (size_t)(n0 + 64 + rA) * K + sl * 8;
  const int ldsbase = wv * 1024;                 // wave-uniform, +lane*16 by HW

  const int nt = K >> 6;                         // K/64 tiles
  // prologue: stage tile 0 into buf 0
  {
    gload16(gA0, (char*)sA[0] + ldsbase);
    gload16(gA1, (char*)sA[0] + 8192 + ldsbase);
    gload16(gB0, (char*)sB[0] + ldsbase);
    gload16(gB1, (char*)sB[0] + 8192 + ldsbase);
  }
  asm volatile("s_waitcnt vmcnt(0)" ::: "memory");
  __syncthreads();

  int cur = 0;
  for (int t = 0; t < nt; t++){
    // stage next tile into buf cur^1 while computing buf cur
    if (t + 1 < nt){
      const int ke = (t + 1) << 6;
      gload16(gA0 + ke, (char*)sA[cur^1] + ldsbase);
      gload16(gA1 + ke, (char*)sA[cur^1] + 8192 + ldsbase);
      gload16(gB0 + ke, (char*)sB[cur^1] + ldsbase);
      gload16(gB1 + ke, (char*)sB[cur^1] + 8192 + ldsbase);
    }
    // compute current tile: frag element idx = row*64 + ((ks*4+lk)^xr)*8
    const __bf16* cA = sA[cur];
    const __bf16* cB = sB[cur];
    #pragma unroll
    for (int ks = 0; ks < 2; ks++){
      const int so = ((ks*4 + lk) ^ xr) * 8;
      bf16x8 af[4], bfr[2];
      #pragma unroll
      for (int i = 0; i < 4; i++) af[i]  = *(const bf16x8*)&cA[(wm + i*16 + li)*64 + so];
      #pragma unroll
      for (int j = 0; j < 2; j++) bfr[j] = *(const bf16x8*)&cB[(wn + j*16 + li)*64 + so];
      #pragma unroll
      for (int i = 0; i < 4; i++)
        #pragma unroll
        for (int j = 0; j < 2; j++) acc[i][j] = mfma16(af[i], bfr[j], acc[i][j]);
    }
    asm volatile("s_waitcnt vmcnt(0)" ::: "memory");
    __syncthreads();
    cur ^= 1;
  }

  #pragma unroll
  for (int i = 0; i < 4; i++){
    #pragma unroll
    for (int j = 0; j < 2; j++){
      int colg = n0 + wn + j*16 + li;
      float bc = b2f(bias[colg]);
      #pragma unroll
      for (int r2 = 0; r2 < 4; r2++){
        int rowg = m0 + wm + i*16 + lk*4 + r2;
        if (rowg < M){
          float vv = acc[i][j][r2] + bc;
          if (flags & 1) vv = gelu_t(vv);
          if (flags & 2) vv += res[(size_t)rowg * N + colg];
          if (flags & 4){
            size_t oidx = (size_t)(row_off + rowg) * N + colg;
            if (df == 0) ((float*)out)[oidx] = vv;
            else         ((bf*)out)[oidx]    = __float2bfloat16(vv);
          } else {
            ((bf*)out)[(size_t)rowg * N + colg] = __float2bfloat16(vv);
          }
        }
      }
    }
  }
}

// ------------------------------------------------------------------
// Relative-position bias tables per (window-local, head) via MFMA. 300 blocks/batch.
__global__ __launch_bounds__(256) void bias_tables(const bf* __restrict__ qkv,
    const bf* __restrict__ rph, const bf* __restrict__ rpw,
    bf* __restrict__ relHg, bf* __restrict__ relWg){
  const int blk = blockIdx.x;              // w*12 + h, w local 0..24
  const int w = blk / 12, h = blk % 12;
  const int tid = threadIdx.x, wv = tid >> 6, l = tid & 63;
  const int li = l & 15, lk = l >> 4;
  const bf* qbase = qkv + (size_t)w * 197 * 2304 + h * 64;
  const size_t obase = (size_t)blk * 196 * 14;
  for (int g = wv; g < 28; g += 4){
    bool isH = (g < 14);
    int pfix = isH ? g : (g - 14);         // pi for H, pj for W
    int var  = li < 13 ? li : 13;          // pj for H, pi for W (clamped dup lanes 14,15)
    int q = isH ? (1 + pfix*14 + var) : (1 + var*14 + pfix);
    f32x4 acc = {0.f,0.f,0.f,0.f};
    const bf* rp = isH ? rph : rpw;
    #pragma unroll
    for (int s = 0; s < 2; s++){
      bf16x8 a = *(const bf16x8*)(qbase + (size_t)q * 2304 + s*32 + lk*8);
      int idx = pfix + 13 - li;
      if (idx < 0) idx = 0;
      bf16x8 b = *(const bf16x8*)(rp + idx * 64 + s*32 + lk*8);
      acc = mfma16(a, b, acc);
    }
    #pragma unroll
    for (int r = 0; r < 4; r++){
      int mrow = lk*4 + r;                 // pj for H, pi for W
      int col = li;                        // kh / kw
      if (mrow <= 13 && col <= 13){
        int qi = isH ? (pfix*14 + mrow) : (mrow*14 + pfix);
        bf* dst = isH ? relHg : relWg;
        dst[obase + (size_t)qi * 14 + col] = __float2bfloat16(acc[r]);
      }
    }
  }
}

// ------------------------------------------------------------------
// Attention per (window-local, head). 300 blocks/batch, 4 waves.
__global__ __launch_bounds__(256) void attn_win(const bf* __restrict__ qkv,
    const bf* __restrict__ relHg, const bf* __restrict__ relWg, bf* __restrict__ aout){
  __shared__ __bf16 Vt[64][232];     // V transposed [c][key], keys 0..223 (pad zero)
  __shared__ __bf16 Pl[4][16][232];  // per-wave P tile [qrow][key]
  const int blk = blockIdx.x;
  const int w = blk / 12, h = blk % 12;
  const int tid = threadIdx.x, wv = tid >> 6, l = tid & 63;
  const int li = l & 15, lk = l >> 4;
  const bf* qp = qkv + (size_t)w * 197 * 2304 + h * 64;
  const bf* kp = qp + 768;
  const bf* vp = qp + 1536;
  {
    const int cc = (tid & 7) * 8, rb = tid >> 3;
    #pragma unroll
    for (int pass = 0; pass < 7; pass++){
      int r = pass * 32 + rb;              // 0..223
      __bf16 vvv[8];
      if (r < 197){
        bf16x8 t = *(const bf16x8*)(vp + (size_t)r * 2304 + cc);
        #pragma unroll
        for (int e = 0; e < 8; e++) vvv[e] = t[e];
      } else {
        #pragma unroll
        for (int e = 0; e < 8; e++) vvv[e] = (__bf16)0.f;
      }
      #pragma unroll
      for (int e = 0; e < 8; e++) Vt[cc + e][r] = vvv[e];
    }
  }
  for (int i = l; i < 256; i += 64) Pl[wv][i >> 4][208 + (i & 15)] = (__bf16)0.f;
  __syncthreads();
  const bf* rHb = relHg + (size_t)blk * 196 * 14;
  const bf* rWb = relWg + (size_t)blk * 196 * 14;
  for (int qt = wv; qt < 13; qt += 4){
    int qrow = qt * 16 + li; if (qrow > 196) qrow = 196;
    bf16x8 qa0 = *(const bf16x8*)(qp + (size_t)qrow * 2304 + lk*8);
    bf16x8 qa1 = *(const bf16x8*)(qp + (size_t)qrow * 2304 + 32 + lk*8);
    f32x4 sc[13];
    #pragma unroll
    for (int ct = 0; ct < 13; ct++){
      int kr = ct * 16 + li; if (kr > 196) kr = 196;
      bf16x8 kb0 = *(const bf16x8*)(kp + (size_t)kr * 2304 + lk*8);
      bf16x8 kb1 = *(const bf16x8*)(kp + (size_t)kr * 2304 + 32 + lk*8);
      f32x4 z = {0.f,0.f,0.f,0.f};
      z = mfma16(qa0, kb0, z);
      z = mfma16(qa1, kb1, z);
      sc[ct] = z;
    }
    float mx[4] = {-3e38f, -3e38f, -3e38f, -3e38f};
    #pragma unroll
    for (int ct = 0; ct < 13; ct++){
      #pragma unroll
      for (int r = 0; r < 4; r++){
        int col = ct * 16 + li;
        int grow = qt * 16 + lk*4 + r;
        float s = sc[ct][r] * 0.125f;      // SCALE = HD^-0.5
        if (col >= 197) s = -1e30f;
        else if (col >= 1 && grow >= 1 && grow < 197){
          int qi = grow - 1, ki = col - 1;
          int kh = ki / 14, kw = ki - kh * 14;
          s += b2f(rHb[qi*14 + kh]) + b2f(rWb[qi*14 + kw]);
        }
        sc[ct][r] = s;
        mx[r] = fmaxf(mx[r], s);
      }
    }
    #pragma unroll
    for (int r = 0; r < 4; r++){
      #pragma unroll
      for (int off = 1; off < 16; off <<= 1) mx[r] = fmaxf(mx[r], __shfl_xor(mx[r], off));
    }
    float den[4] = {0.f,0.f,0.f,0.f};
    #pragma unroll
    for (int ct = 0; ct < 13; ct++)
      #pragma unroll
      for (int r = 0; r < 4; r++){
        float e = __expf(sc[ct][r] - mx[r]);
        sc[ct][r] = e; den[r] += e;
      }
    #pragma unroll
    for (int r = 0; r < 4; r++){
      #pragma unroll
      for (int off = 1; off < 16; off <<= 1) den[r] += __shfl_xor(den[r], off);
      den[r] = 1.f / den[r];
    }
    #pragma unroll
    for (int ct = 0; ct < 13; ct++)
      #pragma unroll
      for (int r = 0; r < 4; r++)
        Pl[wv][lk*4 + r][ct*16 + li] = (__bf16)(sc[ct][r] * den[r]);
    asm volatile("s_waitcnt lgkmcnt(0)" ::: "memory");
    __builtin_amdgcn_sched_barrier(0);
    #pragma unroll
    for (int n = 0; n < 4; n++){
      f32x4 o = {0.f,0.f,0.f,0.f};
      #pragma unroll
      for (int ks = 0; ks < 7; ks++){
        bf16x8 pa = *(const bf16x8*)&Pl[wv][li][ks*32 + lk*8];
        bf16x8 vb = *(const bf16x8*)&Vt[n*16 + li][ks*32 + lk*8];
        o = mfma16(pa, vb, o);
      }
      #pragma unroll
      for (int r = 0; r < 4; r++){
        int grow = qt * 16 + lk*4 + r;
        if (grow < 197)
          aout[((size_t)w * 197 + grow) * 768 + h*64 + n*16 + li] = __float2bfloat16(o[r]);
      }
    }
  }
}

// ------------------------------------------------------------------
// Un-window + cls-mean + residual for ONE batch -> tok2 rows of that batch (fp32).
__global__ __launch_bounds__(256) void unwindow(const void* __restrict__ x, const void* __restrict__ cls,
    const bf* __restrict__ projo, float* __restrict__ tok2, int batch, const int* flag){
  const int f = *flag;
  int t = blockIdx.x;                  // 0..4096 local token
  for (int c = threadIdx.x; c < 768; c += 256){
    float val, add;
    if (t == 0){
      val = ldx(cls, (size_t)batch * 768 + c, f);
      float s = 0.f;
      #pragma unroll
      for (int wi = 0; wi < 25; wi++)
        s += b2f(projo[((size_t)wi * 197) * 768 + c]);
      add = s * 0.04f;                  // 1/25
    } else {
      int idx = t - 1, gh = idx >> 6, gw = idx & 63;
      int wi = gh / 14, pi = gh % 14, wj = gw / 14, pj = gw % 14;
      int wwin = wi*5 + wj, tl = 1 + pi*14 + pj;
      val = ldx(x, ((size_t)batch * 4096 + idx) * 768 + c, f);
      add = b2f(projo[((size_t)wwin * 197 + tl) * 768 + c]);
    }
    tok2[((size_t)batch * 4097 + t) * 768 + c] = val + add;
  }
}

// ------------------------------------------------------------------
// Workspace layout — peak 105,637,248 B (~100.7 MiB). All boundaries exact:
//   [0,256)                   dtype flag
//   [256, 14,156,032)         transposed bf16 weights
//   [14,156,032, 14,182,912)  converted small arrays
//   [14,188,800, 17,481,600)  relH/relW per batch     } MLP-phase reuse:
//   [17,481,600, 25,046,400)  winx_b / attn_ob        }  hbuf  [14,188,800, 20,481,792)
//   [25,046,400, 47,740,800)  qkvB                    }  fc1g  [20,482,048, 45,654,016)
//   [47,740,800, 55,305,600)  projo_b                 }  (no overlap with hbuf/tok2)
//   [55,305,600, 105,637,248) tok2 fp32 (live through MLP)
extern "C" void kernel_launch(void* const* d_in, const int* in_sizes, int n_in,
                              void* d_out, int out_size, void* d_ws, size_t ws_size,
                              hipStream_t stream){
  (void)in_sizes; (void)n_in; (void)out_size; (void)ws_size;
  const void* x      = d_in[0];
  const void* cls    = d_in[1];
  const void* qkv_w  = d_in[2];
  const void* qkv_bv = d_in[3];
  const void* proj_w = d_in[4];
  const void* proj_bv= d_in[5];
  const void* rph    = d_in[6];
  const void* rpw    = d_in[7];
  const void* n1s    = d_in[8];
  const void* n1b    = d_in[9];
  const void* n2s    = d_in[10];
  const void* n2b    = d_in[11];
  const void* fc1_w  = d_in[12];
  const void* fc1_bv = d_in[13];
  const void* fc2_w  = d_in[14];
  const void* fc2_bv = d_in[15];

  char* ws = (char*)d_ws;
  int* flagp  = (int*)(ws + 0);
  bf* wt_qkv  = (bf*)(ws + 256);
  bf* wt_proj = (bf*)(ws + 3539200);
  bf* wt_fc1  = (bf*)(ws + 4718848);
  bf* wt_fc2  = (bf*)(ws + 9437440);
  bf* c_qkv_b = (bf*)(ws + 14156032);   // 2304
  bf* c_proj_b= (bf*)(ws + 14160640);   // 768
  bf* c_fc1_b = (bf*)(ws + 14162176);   // 3072
  bf* c_fc2_b = (bf*)(ws + 14168320);   // 768
  bf* c_n1s   = (bf*)(ws + 14169856);   // 768
  bf* c_n1b   = (bf*)(ws + 14171392);   // 768
  bf* c_n2s   = (bf*)(ws + 14172928);   // 768
  bf* c_n2b   = (bf*)(ws + 14174464);   // 768
  bf* c_rph   = (bf*)(ws + 14176000);   // 1728
  bf* c_rpw   = (bf*)(ws + 14179456);   // 1728
  bf* relH_b  = (bf*)(ws + 14188800);   // 25*12*196*14
  bf* relW_b  = relH_b + 823200;
  bf* winx_b  = (bf*)(ws + 17481600);   // 4925x768
  bf* attn_ob = winx_b;                  // reuse
  bf* qkvB    = (bf*)(ws + 25046400);   // 4925x2304
  bf* projo_b = (bf*)(ws + 47740800);   // 4925x768
  float* tok2 = (float*)(ws + 55305600);// 16388x768 fp32
  bf* hbuf    = (bf*)(ws + 14188800);   // 4097x768 chunk (MLP phase), ends 20,481,792
  bf* fc1g    = (bf*)(ws + 20482048);   // 4097x3072 chunk, ends 45,654,016

  detect_dtype<<<1, 1, 0, stream>>>(n1s, flagp);

  conv_bf16<<<9,  256, 0, stream>>>(qkv_bv,  c_qkv_b, 2304, flagp);
  conv_bf16<<<3,  256, 0, stream>>>(proj_bv, c_proj_b, 768, flagp);
  conv_bf16<<<12, 256, 0, stream>>>(fc1_bv,  c_fc1_b, 3072, flagp);
  conv_bf16<<<3,  256, 0, stream>>>(fc2_bv,  c_fc2_b,  768, flagp);
  conv_bf16<<<3,  256, 0, stream>>>(n1s, c_n1s, 768, flagp);
  conv_bf16<<<3,  256, 0, stream>>>(n1b, c_n1b, 768, flagp);
  conv_bf16<<<3,  256, 0, stream>>>(n2s, c_n2s, 768, flagp);
  conv_bf16<<<3,  256, 0, stream>>>(n2b, c_n2b, 768, flagp);
  conv_bf16<<<7,  256, 0, stream>>>(rph, c_rph, 1728, flagp);
  conv_bf16<<<7,  256, 0, stream>>>(rpw, c_rpw, 1728, flagp);

  transpose_w<<<dim3(72, 24), 256, 0, stream>>>(qkv_w, wt_qkv, 768, 2304, flagp);
  transpose_w<<<dim3(24, 24), 256, 0, stream>>>(proj_w, wt_proj, 768, 768, flagp);
  transpose_w<<<dim3(96, 24), 256, 0, stream>>>(fc1_w, wt_fc1, 768, 3072, flagp);
  transpose_w<<<dim3(24, 96), 256, 0, stream>>>(fc2_w, wt_fc2, 3072, 768, flagp);

  for (int b = 0; b < 4; b++){
    ln_window<<<4925, 256, 0, stream>>>(x, cls, c_n1s, c_n1b, winx_b, b, flagp);
    gemm128<<<dim3(18, 39), 512, 0, stream>>>(winx_b, wt_qkv, c_qkv_b, nullptr, qkvB,
                                              4925, 2304, 768, 0, flagp, 0);
    bias_tables<<<300, 256, 0, stream>>>(qkvB, c_rph, c_rpw, relH_b, relW_b);
    attn_win<<<300, 256, 0, stream>>>(qkvB, relH_b, relW_b, attn_ob);
    gemm128<<<dim3(6, 39), 512, 0, stream>>>(attn_ob, wt_proj, c_proj_b, nullptr, projo_b,
                                             4925, 768, 768, 0, flagp, 0);
    unwindow<<<4097, 256, 0, stream>>>(x, cls, projo_b, tok2, b, flagp);
  }

  for (int c = 0; c < 4; c++){
    ln_f32<<<4097, 256, 0, stream>>>(tok2 + (size_t)c * 4097 * 768, c_n2s, c_n2b, hbuf);
    gemm128<<<dim3(24, 33), 512, 0, stream>>>(hbuf, wt_fc1, c_fc1_b, nullptr, fc1g,
                                              4097, 3072, 768, 1, flagp, 0);
    gemm128<<<dim3(6, 33), 512, 0, stream>>>(fc1g, wt_fc2, c_fc2_b,
                                             tok2 + (size_t)c * 4097 * 768,
                                             d_out,
                                             4097, 768, 3072, 2 | 4, flagp, c * 4097);
  }
}

// Round 8
// 982.014 us; speedup vs baseline: 1.3200x; 1.0771x over previous
//
#include <hip/hip_runtime.h>
#include <hip/hip_bf16.h>

typedef __hip_bfloat16 bf;
typedef __bf16 bf16x8 __attribute__((ext_vector_type(8)));
typedef float f32x4 __attribute__((ext_vector_type(4)));
typedef unsigned short u16x4 __attribute__((ext_vector_type(4)));

#define DEVI __device__ __forceinline__

DEVI float b2f(bf v){ return __bfloat162float(v); }

DEVI float bfbits(unsigned short v){
  unsigned u = (unsigned)v << 16; float f; __builtin_memcpy(&f, &u, 4); return f;
}

// dual-path external load: f==0 -> fp32, f==1 -> bf16
DEVI float ldx(const void* p, size_t i, int f){
  return f ? __bfloat162float(((const bf*)p)[i]) : ((const float*)p)[i];
}

DEVI f32x4 mfma16(bf16x8 a, bf16x8 b, f32x4 c){
  return __builtin_amdgcn_mfma_f32_16x16x32_bf16(a, b, c, 0, 0, 0);
}

DEVI float gelu_t(float x){
  float u = 0.7978845608028654f * (x + 0.044715f * x * x * x);
  u = fminf(fmaxf(u, -30.f), 30.f);
  float e = __expf(2.f * u);
  return 0.5f * x * (1.f + (e - 1.f) / (e + 1.f));
}

// async global->LDS, 16B per lane, wave-uniform LDS base (HW adds lane*16)
DEVI void gload16(const bf* g, char* l){
  __builtin_amdgcn_global_load_lds((const __attribute__((address_space(1))) void*)g,
                                   (__attribute__((address_space(3))) void*)l, 16, 0, 0);
}

// ------------------------------------------------------------------
// dtype detect: norm1_s == ones. fp32 word = 0x3F800000; bf16 pair = 0x3F803F80.
__global__ void detect_dtype(const void* n1s, int* flag){
  unsigned u = *(const unsigned*)n1s;
  *flag = (u == 0x3F800000u) ? 0 : 1;
}

// convert external array -> bf16 buffer (dual path)
__global__ __launch_bounds__(256) void conv_bf16(const void* src, bf* dst, int n, const int* flag){
  int f = *flag;
  int i = blockIdx.x * 256 + threadIdx.x;
  if (i < n) dst[i] = f ? ((const bf*)src)[i] : __float2bfloat16(((const float*)src)[i]);
}

// ------------------------------------------------------------------
// transpose+convert: Wt[n][k] = bf16(W[k][n])   (K, N multiples of 32)
__global__ __launch_bounds__(256) void transpose_w(const void* __restrict__ W, bf* __restrict__ Wt,
                                                   int K, int N, const int* flag){
  __shared__ bf tile[32][33];
  const int f = *flag;
  int n0 = blockIdx.x * 32, k0 = blockIdx.y * 32;
  int tx = threadIdx.x & 31, ty = threadIdx.x >> 5;
  #pragma unroll
  for (int i = ty; i < 32; i += 8)
    tile[i][tx] = __float2bfloat16(ldx(W, (size_t)(k0 + i) * N + n0 + tx, f));
  __syncthreads();
  #pragma unroll
  for (int i = ty; i < 32; i += 8) Wt[(size_t)(n0 + i) * K + k0 + tx] = tile[tx][i];
}

// ------------------------------------------------------------------
DEVI void blockreduce2(float& s, float& s2){
  #pragma unroll
  for (int off = 32; off > 0; off >>= 1){
    s  += __shfl_down(s, off);
    s2 += __shfl_down(s2, off);
  }
  __shared__ float sh[8];
  int wv = threadIdx.x >> 6;
  if ((threadIdx.x & 63) == 0){ sh[wv*2] = s; sh[wv*2+1] = s2; }
  __syncthreads();
  s  = sh[0] + sh[2] + sh[4] + sh[6];
  s2 = sh[1] + sh[3] + sh[5] + sh[7];
}

// LN1 fused with window gather for ONE batch (25 windows, 4925 rows local).
__global__ __launch_bounds__(256) void ln_window(const void* __restrict__ x, const void* __restrict__ cls,
    const bf* __restrict__ g, const bf* __restrict__ bb, bf* __restrict__ winx, int batch,
    const int* flag){
  const int f = *flag;
  int row = blockIdx.x;                 // 0..4924 (local)
  int wid = row / 197, p = row % 197;   // wid 0..24
  int wi = wid / 5, wj = wid % 5;
  bf* dst = winx + (size_t)row * 768;
  int tid = threadIdx.x;
  const void* src = nullptr;
  size_t base = 0;
  if (p == 0){ src = cls; base = (size_t)batch * 768; }
  else {
    int pi = (p - 1) / 14, pj = (p - 1) % 14;
    int gh = wi * 14 + pi, gw = wj * 14 + pj;
    if (gh < 64 && gw < 64){ src = x; base = ((size_t)((batch * 64 + gh) * 64 + gw)) * 768; }
  }
  if (!src){
    for (int c = tid; c < 768; c += 256) dst[c] = __float2bfloat16(0.f);
    return;
  }
  float v[3]; float s = 0.f, s2 = 0.f;
  #pragma unroll
  for (int k = 0; k < 3; k++){ v[k] = ldx(src, base + tid + k*256, f); s += v[k]; s2 += v[k]*v[k]; }
  blockreduce2(s, s2);
  float mu  = s  * (1.f/768.f);
  float var = fmaxf(s2 * (1.f/768.f) - mu*mu, 0.f);
  float rs  = rsqrtf(var + 1e-6f);
  #pragma unroll
  for (int k = 0; k < 3; k++){
    int c = tid + k*256;
    dst[c] = __float2bfloat16((v[k]-mu)*rs*b2f(g[c]) + b2f(bb[c]));
  }
}

// LN over fp32 rows -> bf16
__global__ __launch_bounds__(256) void ln_f32(const float* __restrict__ in, const bf* __restrict__ g,
    const bf* __restrict__ bb, bf* __restrict__ outb){
  size_t row = blockIdx.x;
  const float* src = in + row * 768;
  bf* dst = outb + row * 768;
  int tid = threadIdx.x;
  float v[3]; float s = 0.f, s2 = 0.f;
  #pragma unroll
  for (int k = 0; k < 3; k++){ v[k] = src[tid + k*256]; s += v[k]; s2 += v[k]*v[k]; }
  blockreduce2(s, s2);
  float mu  = s  * (1.f/768.f);
  float var = fmaxf(s2 * (1.f/768.f) - mu*mu, 0.f);
  float rs  = rsqrtf(var + 1e-6f);
  #pragma unroll
  for (int k = 0; k < 3; k++){
    int c = tid + k*256;
    dst[c] = __float2bfloat16((v[k]-mu)*rs*b2f(g[c]) + b2f(bb[c]));
  }
}

// ------------------------------------------------------------------
// GEMM: out[M,N] = act(A[M,K] @ Bt[N,K]^T + bias) (+res)
// 128x128 tile, BK=64, 8 waves, double-buffered LDS, XOR-swizzled, T1 swizzle.
__global__ __launch_bounds__(512) void gemm128(const bf* __restrict__ A, const bf* __restrict__ Bt,
    const bf* __restrict__ bias, const float* __restrict__ res, void* __restrict__ out,
    int M, int N, int K, int flags, const int* dflag, int row_off)
{
  __shared__ __bf16 sA[2][128*64];
  __shared__ __bf16 sB[2][128*64];
  const int df = *dflag;
  const int gx = gridDim.x;
  const int nwg = gx * gridDim.y;
  const int lin = blockIdx.y * gx + blockIdx.x;
  const int q = nwg >> 3, r = nwg & 7;
  const int xcd = lin & 7, pos = lin >> 3;
  const int logical = (xcd < r ? xcd * (q + 1) : r * (q + 1) + (xcd - r) * q) + pos;
  const int m0 = (logical / gx) * 128, n0 = (logical % gx) * 128;

  const int tid = threadIdx.x, wv = tid >> 6, l = tid & 63;
  const int wm = (wv >> 2) * 64;
  const int wn = (wv & 3) * 32;
  const int li = l & 15, lk = l >> 4;
  const int xr = li & 7;

  f32x4 acc[4][2];
  #pragma unroll
  for (int i = 0; i < 4; i++)
    #pragma unroll
    for (int j = 0; j < 2; j++){ f32x4 z = {0.f,0.f,0.f,0.f}; acc[i][j] = z; }

  const int rA = tid >> 3;
  const int sl = (tid & 7) ^ (rA & 7);
  const bf* gA0 = A  + (size_t)(m0 + rA)      * K + sl * 8;
  const bf* gA1 = A  + (size_t)(m0 + 64 + rA) * K + sl * 8;
  const bf* gB0 = Bt + (size_t)(n0 + rA)      * K + sl * 8;
  const bf* gB1 = Bt + (size_t)(n0 + 64 + rA) * K + sl * 8;
  const int ldsbase = wv * 1024;

  const int nt = K >> 6;
  {
    gload16(gA0, (char*)sA[0] + ldsbase);
    gload16(gA1, (char*)sA[0] + 8192 + ldsbase);
    gload16(gB0, (char*)sB[0] + ldsbase);
    gload16(gB1, (char*)sB[0] + 8192 + ldsbase);
  }
  asm volatile("s_waitcnt vmcnt(0)" ::: "memory");
  __syncthreads();

  int cur = 0;
  for (int t = 0; t < nt; t++){
    if (t + 1 < nt){
      const int ke = (t + 1) << 6;
      gload16(gA0 + ke, (char*)sA[cur^1] + ldsbase);
      gload16(gA1 + ke, (char*)sA[cur^1] + 8192 + ldsbase);
      gload16(gB0 + ke, (char*)sB[cur^1] + ldsbase);
      gload16(gB1 + ke, (char*)sB[cur^1] + 8192 + ldsbase);
    }
    const __bf16* cA = sA[cur];
    const __bf16* cB = sB[cur];
    #pragma unroll
    for (int ks = 0; ks < 2; ks++){
      const int so = ((ks*4 + lk) ^ xr) * 8;
      bf16x8 af[4], bfr[2];
      #pragma unroll
      for (int i = 0; i < 4; i++) af[i]  = *(const bf16x8*)&cA[(wm + i*16 + li)*64 + so];
      #pragma unroll
      for (int j = 0; j < 2; j++) bfr[j] = *(const bf16x8*)&cB[(wn + j*16 + li)*64 + so];
      #pragma unroll
      for (int i = 0; i < 4; i++)
        #pragma unroll
        for (int j = 0; j < 2; j++) acc[i][j] = mfma16(af[i], bfr[j], acc[i][j]);
    }
    asm volatile("s_waitcnt vmcnt(0)" ::: "memory");
    __syncthreads();
    cur ^= 1;
  }

  #pragma unroll
  for (int i = 0; i < 4; i++){
    #pragma unroll
    for (int j = 0; j < 2; j++){
      int colg = n0 + wn + j*16 + li;
      float bc = b2f(bias[colg]);
      #pragma unroll
      for (int r2 = 0; r2 < 4; r2++){
        int rowg = m0 + wm + i*16 + lk*4 + r2;
        if (rowg < M){
          float vv = acc[i][j][r2] + bc;
          if (flags & 1) vv = gelu_t(vv);
          if (flags & 2) vv += res[(size_t)rowg * N + colg];
          if (flags & 4){
            size_t oidx = (size_t)(row_off + rowg) * N + colg;
            if (df == 0) ((float*)out)[oidx] = vv;
            else         ((bf*)out)[oidx]    = __float2bfloat16(vv);
          } else {
            ((bf*)out)[(size_t)rowg * N + colg] = __float2bfloat16(vv);
          }
        }
      }
    }
  }
}

// ------------------------------------------------------------------
// Relative-position bias tables per (window-local, head), TRANSPOSED layout:
// relT[blk] = { relHT[14][200], relWT[14][200] } with relHT[kh][grow] where
// grow = qi+1 (grow=0 slot unused/garbage; masked by consumer). blk = w*12+h.
__global__ __launch_bounds__(256) void bias_tables(const bf* __restrict__ qkv,
    const bf* __restrict__ rph, const bf* __restrict__ rpw, bf* __restrict__ relT){
  const int blk = blockIdx.x;              // w*12 + h, w local 0..24
  const int w = blk / 12, h = blk % 12;
  const int tid = threadIdx.x, wv = tid >> 6, l = tid & 63;
  const int li = l & 15, lk = l >> 4;
  const bf* qbase = qkv + (size_t)w * 197 * 2304 + h * 64;
  bf* tbase = relT + (size_t)blk * 5600;
  for (int g = wv; g < 28; g += 4){
    bool isH = (g < 14);
    int pfix = isH ? g : (g - 14);         // pi for H, pj for W
    int var  = li < 13 ? li : 13;          // pj for H, pi for W (clamped dup lanes 14,15)
    int q = isH ? (1 + pfix*14 + var) : (1 + var*14 + pfix);
    f32x4 acc = {0.f,0.f,0.f,0.f};
    const bf* rp = isH ? rph : rpw;
    #pragma unroll
    for (int s = 0; s < 2; s++){
      bf16x8 a = *(const bf16x8*)(qbase + (size_t)q * 2304 + s*32 + lk*8);
      int idx = pfix + 13 - li;
      if (idx < 0) idx = 0;
      bf16x8 b = *(const bf16x8*)(rp + idx * 64 + s*32 + lk*8);
      acc = mfma16(a, b, acc);
    }
    #pragma unroll
    for (int r = 0; r < 4; r++){
      int mrow = lk*4 + r;                 // pj for H, pi for W
      int col = li;                        // kh / kw
      if (mrow <= 13 && col <= 13){
        int qi = isH ? (pfix*14 + mrow) : (mrow*14 + pfix);
        tbase[(isH ? 0 : 2800) + col*200 + qi + 1] = __float2bfloat16(acc[r]);
      }
    }
  }
}

// ------------------------------------------------------------------
// Attention per (window-local, head, q-half). 600 blocks/batch, 4 waves.
// half 0: q-tiles 0..6, half 1: 7..12. Vectorized bias loads from relT.
__global__ __launch_bounds__(256) void attn_win(const bf* __restrict__ qkv,
    const bf* __restrict__ relT, bf* __restrict__ aout){
  __shared__ __bf16 Vt[64][232];     // V transposed [c][key], keys 0..223 (pad zero)
  __shared__ __bf16 Pl[4][16][232];  // per-wave P tile [qrow][key]
  const int blk = blockIdx.x;
  const int wh = blk >> 1, half = blk & 1;
  const int w = wh / 12, h = wh % 12;
  const int tid = threadIdx.x, wv = tid >> 6, l = tid & 63;
  const int li = l & 15, lk = l >> 4;
  const bf* qp = qkv + (size_t)w * 197 * 2304 + h * 64;
  const bf* kp = qp + 768;
  const bf* vp = qp + 1536;
  {
    const int cc = (tid & 7) * 8, rb = tid >> 3;
    #pragma unroll
    for (int pass = 0; pass < 7; pass++){
      int r = pass * 32 + rb;              // 0..223
      __bf16 vvv[8];
      if (r < 197){
        bf16x8 t = *(const bf16x8*)(vp + (size_t)r * 2304 + cc);
        #pragma unroll
        for (int e = 0; e < 8; e++) vvv[e] = t[e];
      } else {
        #pragma unroll
        for (int e = 0; e < 8; e++) vvv[e] = (__bf16)0.f;
      }
      #pragma unroll
      for (int e = 0; e < 8; e++) Vt[cc + e][r] = vvv[e];
    }
  }
  for (int i = l; i < 256; i += 64) Pl[wv][i >> 4][208 + (i & 15)] = (__bf16)0.f;
  __syncthreads();
  const bf* rHT = relT + (size_t)wh * 5600;
  const bf* rWT = rHT + 2800;
  const int qt0 = half * 7;
  const int nqt = half ? 6 : 7;
  for (int qt_l = wv; qt_l < nqt; qt_l += 4){
    const int qt = qt0 + qt_l;
    const int grow0 = qt*16 + lk*4;        // multiple of 4
    int qrow = qt * 16 + li; if (qrow > 196) qrow = 196;
    bf16x8 qa0 = *(const bf16x8*)(qp + (size_t)qrow * 2304 + lk*8);
    bf16x8 qa1 = *(const bf16x8*)(qp + (size_t)qrow * 2304 + 32 + lk*8);
    f32x4 sc[13];
    #pragma unroll
    for (int ct = 0; ct < 13; ct++){
      int kr = ct * 16 + li; if (kr > 196) kr = 196;
      bf16x8 kb0 = *(const bf16x8*)(kp + (size_t)kr * 2304 + lk*8);
      bf16x8 kb1 = *(const bf16x8*)(kp + (size_t)kr * 2304 + 32 + lk*8);
      f32x4 z = {0.f,0.f,0.f,0.f};
      z = mfma16(qa0, kb0, z);
      z = mfma16(qa1, kb1, z);
      sc[ct] = z;
    }
    float mx[4] = {-3e38f, -3e38f, -3e38f, -3e38f};
    #pragma unroll
    for (int ct = 0; ct < 13; ct++){
      const int col = ct * 16 + li;
      const int kiq = col >= 1 ? col - 1 : 0;
      const int kh = (kiq * 4682) >> 16;           // exact /14 for kiq<=206
      const int kw = kiq - kh * 14;
      const u16x4 rh4 = *(const u16x4*)(rHT + kh*200 + grow0);
      const u16x4 rw4 = *(const u16x4*)(rWT + kw*200 + grow0);
      #pragma unroll
      for (int r = 0; r < 4; r++){
        int grow = grow0 + r;
        float s = sc[ct][r] * 0.125f;      // SCALE = HD^-0.5
        if (col >= 197) s = -1e30f;
        else if (col >= 1 && grow >= 1 && grow < 197)
          s += bfbits(rh4[r]) + bfbits(rw4[r]);
        sc[ct][r] = s;
        mx[r] = fmaxf(mx[r], s);
      }
    }
    #pragma unroll
    for (int r = 0; r < 4; r++){
      #pragma unroll
      for (int off = 1; off < 16; off <<= 1) mx[r] = fmaxf(mx[r], __shfl_xor(mx[r], off));
    }
    float den[4] = {0.f,0.f,0.f,0.f};
    #pragma unroll
    for (int ct = 0; ct < 13; ct++)
      #pragma unroll
      for (int r = 0; r < 4; r++){
        float e = __expf(sc[ct][r] - mx[r]);
        sc[ct][r] = e; den[r] += e;
      }
    #pragma unroll
    for (int r = 0; r < 4; r++){
      #pragma unroll
      for (int off = 1; off < 16; off <<= 1) den[r] += __shfl_xor(den[r], off);
      den[r] = 1.f / den[r];
    }
    #pragma unroll
    for (int ct = 0; ct < 13; ct++)
      #pragma unroll
      for (int r = 0; r < 4; r++)
        Pl[wv][lk*4 + r][ct*16 + li] = (__bf16)(sc[ct][r] * den[r]);
    asm volatile("s_waitcnt lgkmcnt(0)" ::: "memory");
    __builtin_amdgcn_sched_barrier(0);
    #pragma unroll
    for (int n = 0; n < 4; n++){
      f32x4 o = {0.f,0.f,0.f,0.f};
      #pragma unroll
      for (int ks = 0; ks < 7; ks++){
        bf16x8 pa = *(const bf16x8*)&Pl[wv][li][ks*32 + lk*8];
        bf16x8 vb = *(const bf16x8*)&Vt[n*16 + li][ks*32 + lk*8];
        o = mfma16(pa, vb, o);
      }
      #pragma unroll
      for (int r = 0; r < 4; r++){
        int grow = qt * 16 + lk*4 + r;
        if (grow < 197)
          aout[((size_t)w * 197 + grow) * 768 + h*64 + n*16 + li] = __float2bfloat16(o[r]);
      }
    }
  }
}

// ------------------------------------------------------------------
// Un-window + cls-mean + residual for ONE batch -> tok2 rows of that batch (fp32).
__global__ __launch_bounds__(256) void unwindow(const void* __restrict__ x, const void* __restrict__ cls,
    const bf* __restrict__ projo, float* __restrict__ tok2, int batch, const int* flag){
  const int f = *flag;
  int t = blockIdx.x;                  // 0..4096 local token
  for (int c = threadIdx.x; c < 768; c += 256){
    float val, add;
    if (t == 0){
      val = ldx(cls, (size_t)batch * 768 + c, f);
      float s = 0.f;
      #pragma unroll
      for (int wi = 0; wi < 25; wi++)
        s += b2f(projo[((size_t)wi * 197) * 768 + c]);
      add = s * 0.04f;                  // 1/25
    } else {
      int idx = t - 1, gh = idx >> 6, gw = idx & 63;
      int wi = gh / 14, pi = gh % 14, wj = gw / 14, pj = gw % 14;
      int wwin = wi*5 + wj, tl = 1 + pi*14 + pj;
      val = ldx(x, ((size_t)batch * 4096 + idx) * 768 + c, f);
      add = b2f(projo[((size_t)wwin * 197 + tl) * 768 + c]);
    }
    tok2[((size_t)batch * 4097 + t) * 768 + c] = val + add;
  }
}

// ------------------------------------------------------------------
// Workspace layout — peak 105,637,248 B. Key aliases (stream-order safe):
//   relT (bias tables, 3.36 MB) lives in the projo_b region [47,740,800, ...):
//   written by bias_tables, read by attn_win, dead before proj-gemm writes projo_b.
extern "C" void kernel_launch(void* const* d_in, const int* in_sizes, int n_in,
                              void* d_out, int out_size, void* d_ws, size_t ws_size,
                              hipStream_t stream){
  (void)in_sizes; (void)n_in; (void)out_size; (void)ws_size;
  const void* x      = d_in[0];
  const void* cls    = d_in[1];
  const void* qkv_w  = d_in[2];
  const void* qkv_bv = d_in[3];
  const void* proj_w = d_in[4];
  const void* proj_bv= d_in[5];
  const void* rph    = d_in[6];
  const void* rpw    = d_in[7];
  const void* n1s    = d_in[8];
  const void* n1b    = d_in[9];
  const void* n2s    = d_in[10];
  const void* n2b    = d_in[11];
  const void* fc1_w  = d_in[12];
  const void* fc1_bv = d_in[13];
  const void* fc2_w  = d_in[14];
  const void* fc2_bv = d_in[15];

  char* ws = (char*)d_ws;
  int* flagp  = (int*)(ws + 0);
  bf* wt_qkv  = (bf*)(ws + 256);
  bf* wt_proj = (bf*)(ws + 3539200);
  bf* wt_fc1  = (bf*)(ws + 4718848);
  bf* wt_fc2  = (bf*)(ws + 9437440);
  bf* c_qkv_b = (bf*)(ws + 14156032);   // 2304
  bf* c_proj_b= (bf*)(ws + 14160640);   // 768
  bf* c_fc1_b = (bf*)(ws + 14162176);   // 3072
  bf* c_fc2_b = (bf*)(ws + 14168320);   // 768
  bf* c_n1s   = (bf*)(ws + 14169856);   // 768
  bf* c_n1b   = (bf*)(ws + 14171392);   // 768
  bf* c_n2s   = (bf*)(ws + 14172928);   // 768
  bf* c_n2b   = (bf*)(ws + 14174464);   // 768
  bf* c_rph   = (bf*)(ws + 14176000);   // 1728
  bf* c_rpw   = (bf*)(ws + 14179456);   // 1728
  bf* winx_b  = (bf*)(ws + 17481600);   // 4925x768
  bf* attn_ob = winx_b;                  // reuse
  bf* qkvB    = (bf*)(ws + 25046400);   // 4925x2304
  bf* projo_b = (bf*)(ws + 47740800);   // 4925x768
  bf* relT    = (bf*)(ws + 47740800);   // alias: 300*2*14*200 bf16 = 3.36 MB (dead before projo)
  float* tok2 = (float*)(ws + 55305600);// 16388x768 fp32
  bf* hbuf    = (bf*)(ws + 14188800);   // 4097x768 chunk (MLP phase)
  bf* fc1g    = (bf*)(ws + 20482048);   // 4097x3072 chunk

  detect_dtype<<<1, 1, 0, stream>>>(n1s, flagp);

  conv_bf16<<<9,  256, 0, stream>>>(qkv_bv,  c_qkv_b, 2304, flagp);
  conv_bf16<<<3,  256, 0, stream>>>(proj_bv, c_proj_b, 768, flagp);
  conv_bf16<<<12, 256, 0, stream>>>(fc1_bv,  c_fc1_b, 3072, flagp);
  conv_bf16<<<3,  256, 0, stream>>>(fc2_bv,  c_fc2_b,  768, flagp);
  conv_bf16<<<3,  256, 0, stream>>>(n1s, c_n1s, 768, flagp);
  conv_bf16<<<3,  256, 0, stream>>>(n1b, c_n1b, 768, flagp);
  conv_bf16<<<3,  256, 0, stream>>>(n2s, c_n2s, 768, flagp);
  conv_bf16<<<3,  256, 0, stream>>>(n2b, c_n2b, 768, flagp);
  conv_bf16<<<7,  256, 0, stream>>>(rph, c_rph, 1728, flagp);
  conv_bf16<<<7,  256, 0, stream>>>(rpw, c_rpw, 1728, flagp);

  transpose_w<<<dim3(72, 24), 256, 0, stream>>>(qkv_w, wt_qkv, 768, 2304, flagp);
  transpose_w<<<dim3(24, 24), 256, 0, stream>>>(proj_w, wt_proj, 768, 768, flagp);
  transpose_w<<<dim3(96, 24), 256, 0, stream>>>(fc1_w, wt_fc1, 768, 3072, flagp);
  transpose_w<<<dim3(24, 96), 256, 0, stream>>>(fc2_w, wt_fc2, 3072, 768, flagp);

  for (int b = 0; b < 4; b++){
    ln_window<<<4925, 256, 0, stream>>>(x, cls, c_n1s, c_n1b, winx_b, b, flagp);
    gemm128<<<dim3(18, 39), 512, 0, stream>>>(winx_b, wt_qkv, c_qkv_b, nullptr, qkvB,
                                              4925, 2304, 768, 0, flagp, 0);
    bias_tables<<<300, 256, 0, stream>>>(qkvB, c_rph, c_rpw, relT);
    attn_win<<<600, 256, 0, stream>>>(qkvB, relT, attn_ob);
    gemm128<<<dim3(6, 39), 512, 0, stream>>>(attn_ob, wt_proj, c_proj_b, nullptr, projo_b,
                                             4925, 768, 768, 0, flagp, 0);
    unwindow<<<4097, 256, 0, stream>>>(x, cls, projo_b, tok2, b, flagp);
  }

  for (int c = 0; c < 4; c++){
    ln_f32<<<4097, 256, 0, stream>>>(tok2 + (size_t)c * 4097 * 768, c_n2s, c_n2b, hbuf);
    gemm128<<<dim3(24, 33), 512, 0, stream>>>(hbuf, wt_fc1, c_fc1_b, nullptr, fc1g,
                                              4097, 3072, 768, 1, flagp, 0);
    gemm128<<<dim3(6, 33), 512, 0, stream>>>(fc1g, wt_fc2, c_fc2_b,
                                             tok2 + (size_t)c * 4097 * 768,
                                             d_out,
                                             4097, 768, 3072, 2 | 4, flagp, c * 4097);
  }
}

// Round 9
// 710.405 us; speedup vs baseline: 1.8246x; 1.3823x over previous
//
#include <hip/hip_runtime.h>
#include <hip/hip_bf16.h>

typedef __hip_bfloat16 bf;
typedef __bf16 bf16x8 __attribute__((ext_vector_type(8)));
typedef float f32x4 __attribute__((ext_vector_type(4)));
typedef unsigned short u16x4 __attribute__((ext_vector_type(4)));

#define DEVI __device__ __forceinline__

DEVI float b2f(bf v){ return __bfloat162float(v); }

DEVI float bfbits(unsigned short v){
  unsigned u = (unsigned)v << 16; float f; __builtin_memcpy(&f, &u, 4); return f;
}

// dual-path external load: f==0 -> fp32, f==1 -> bf16
DEVI float ldx(const void* p, size_t i, int f){
  return f ? __bfloat162float(((const bf*)p)[i]) : ((const float*)p)[i];
}

DEVI f32x4 mfma16(bf16x8 a, bf16x8 b, f32x4 c){
  return __builtin_amdgcn_mfma_f32_16x16x32_bf16(a, b, c, 0, 0, 0);
}

DEVI float gelu_t(float x){
  float u = 0.7978845608028654f * (x + 0.044715f * x * x * x);
  u = fminf(fmaxf(u, -30.f), 30.f);
  float e = __expf(2.f * u);
  return 0.5f * x * (1.f + (e - 1.f) / (e + 1.f));
}

// async global->LDS, 16B per lane, wave-uniform LDS base (HW adds lane*16)
DEVI void gload16(const bf* g, char* l){
  __builtin_amdgcn_global_load_lds((const __attribute__((address_space(1))) void*)g,
                                   (__attribute__((address_space(3))) void*)l, 16, 0, 0);
}

// ------------------------------------------------------------------
// dtype detect: norm1_s == ones. fp32 word = 0x3F800000; bf16 pair = 0x3F803F80.
__global__ void detect_dtype(const void* n1s, int* flag){
  unsigned u = *(const unsigned*)n1s;
  *flag = (u == 0x3F800000u) ? 0 : 1;
}

// convert external array -> bf16 buffer (dual path)
__global__ __launch_bounds__(256) void conv_bf16(const void* src, bf* dst, int n, const int* flag){
  int f = *flag;
  int i = blockIdx.x * 256 + threadIdx.x;
  if (i < n) dst[i] = f ? ((const bf*)src)[i] : __float2bfloat16(((const float*)src)[i]);
}

// ------------------------------------------------------------------
// transpose+convert: Wt[n][k] = bf16(W[k][n])   (K, N multiples of 32)
__global__ __launch_bounds__(256) void transpose_w(const void* __restrict__ W, bf* __restrict__ Wt,
                                                   int K, int N, const int* flag){
  __shared__ bf tile[32][33];
  const int f = *flag;
  int n0 = blockIdx.x * 32, k0 = blockIdx.y * 32;
  int tx = threadIdx.x & 31, ty = threadIdx.x >> 5;
  #pragma unroll
  for (int i = ty; i < 32; i += 8)
    tile[i][tx] = __float2bfloat16(ldx(W, (size_t)(k0 + i) * N + n0 + tx, f));
  __syncthreads();
  #pragma unroll
  for (int i = ty; i < 32; i += 8) Wt[(size_t)(n0 + i) * K + k0 + tx] = tile[tx][i];
}

// ------------------------------------------------------------------
DEVI void blockreduce2(float& s, float& s2){
  #pragma unroll
  for (int off = 32; off > 0; off >>= 1){
    s  += __shfl_down(s, off);
    s2 += __shfl_down(s2, off);
  }
  __shared__ float sh[8];
  int wv = threadIdx.x >> 6;
  if ((threadIdx.x & 63) == 0){ sh[wv*2] = s; sh[wv*2+1] = s2; }
  __syncthreads();
  s  = sh[0] + sh[2] + sh[4] + sh[6];
  s2 = sh[1] + sh[3] + sh[5] + sh[7];
}

// LN1 fused with window gather for a chunk of nb batches (grid = nb*4925).
__global__ __launch_bounds__(256) void ln_window(const void* __restrict__ x, const void* __restrict__ cls,
    const bf* __restrict__ g, const bf* __restrict__ bb, bf* __restrict__ winx, int b0,
    const int* flag){
  const int f = *flag;
  int row = blockIdx.x;                 // chunk-local row
  int wid_g = row / 197, p = row % 197;
  int batch = b0 + wid_g / 25;
  int wid = wid_g % 25;
  int wi = wid / 5, wj = wid % 5;
  bf* dst = winx + (size_t)row * 768;
  int tid = threadIdx.x;
  const void* src = nullptr;
  size_t base = 0;
  if (p == 0){ src = cls; base = (size_t)batch * 768; }
  else {
    int pi = (p - 1) / 14, pj = (p - 1) % 14;
    int gh = wi * 14 + pi, gw = wj * 14 + pj;
    if (gh < 64 && gw < 64){ src = x; base = ((size_t)((batch * 64 + gh) * 64 + gw)) * 768; }
  }
  if (!src){
    for (int c = tid; c < 768; c += 256) dst[c] = __float2bfloat16(0.f);
    return;
  }
  float v[3]; float s = 0.f, s2 = 0.f;
  #pragma unroll
  for (int k = 0; k < 3; k++){ v[k] = ldx(src, base + tid + k*256, f); s += v[k]; s2 += v[k]*v[k]; }
  blockreduce2(s, s2);
  float mu  = s  * (1.f/768.f);
  float var = fmaxf(s2 * (1.f/768.f) - mu*mu, 0.f);
  float rs  = rsqrtf(var + 1e-6f);
  #pragma unroll
  for (int k = 0; k < 3; k++){
    int c = tid + k*256;
    dst[c] = __float2bfloat16((v[k]-mu)*rs*b2f(g[c]) + b2f(bb[c]));
  }
}

// LN over fp32 rows -> bf16
__global__ __launch_bounds__(256) void ln_f32(const float* __restrict__ in, const bf* __restrict__ g,
    const bf* __restrict__ bb, bf* __restrict__ outb){
  size_t row = blockIdx.x;
  const float* src = in + row * 768;
  bf* dst = outb + row * 768;
  int tid = threadIdx.x;
  float v[3]; float s = 0.f, s2 = 0.f;
  #pragma unroll
  for (int k = 0; k < 3; k++){ v[k] = src[tid + k*256]; s += v[k]; s2 += v[k]*v[k]; }
  blockreduce2(s, s2);
  float mu  = s  * (1.f/768.f);
  float var = fmaxf(s2 * (1.f/768.f) - mu*mu, 0.f);
  float rs  = rsqrtf(var + 1e-6f);
  #pragma unroll
  for (int k = 0; k < 3; k++){
    int c = tid + k*256;
    dst[c] = __float2bfloat16((v[k]-mu)*rs*b2f(g[c]) + b2f(bb[c]));
  }
}

// ------------------------------------------------------------------
// GEMM: out[M,N] = act(A[M,K] @ Bt[N,K]^T + bias) (+res)
// 128x128 tile, BK=64, 8 waves, double-buffered LDS, XOR-swizzled, T1 swizzle.
__global__ __launch_bounds__(512) void gemm128(const bf* __restrict__ A, const bf* __restrict__ Bt,
    const bf* __restrict__ bias, const float* __restrict__ res, void* __restrict__ out,
    int M, int N, int K, int flags, const int* dflag, int row_off)
{
  __shared__ __bf16 sA[2][128*64];
  __shared__ __bf16 sB[2][128*64];
  const int df = *dflag;
  const int gx = gridDim.x;
  const int nwg = gx * gridDim.y;
  const int lin = blockIdx.y * gx + blockIdx.x;
  const int q = nwg >> 3, r = nwg & 7;
  const int xcd = lin & 7, pos = lin >> 3;
  const int logical = (xcd < r ? xcd * (q + 1) : r * (q + 1) + (xcd - r) * q) + pos;
  const int m0 = (logical / gx) * 128, n0 = (logical % gx) * 128;

  const int tid = threadIdx.x, wv = tid >> 6, l = tid & 63;
  const int wm = (wv >> 2) * 64;
  const int wn = (wv & 3) * 32;
  const int li = l & 15, lk = l >> 4;
  const int xr = li & 7;

  f32x4 acc[4][2];
  #pragma unroll
  for (int i = 0; i < 4; i++)
    #pragma unroll
    for (int j = 0; j < 2; j++){ f32x4 z = {0.f,0.f,0.f,0.f}; acc[i][j] = z; }

  const int rA = tid >> 3;
  const int sl = (tid & 7) ^ (rA & 7);
  const bf* gA0 = A  + (size_t)(m0 + rA)      * K + sl * 8;
  const bf* gA1 = A  + (size_t)(m0 + 64 + rA) * K + sl * 8;
  const bf* gB0 = Bt + (size_t)(n0 + rA)      * K + sl * 8;
  const bf* gB1 = Bt + (size_t)(n0 + 64 + rA) * K + sl * 8;
  const int ldsbase = wv * 1024;

  const int nt = K >> 6;
  {
    gload16(gA0, (char*)sA[0] + ldsbase);
    gload16(gA1, (char*)sA[0] + 8192 + ldsbase);
    gload16(gB0, (char*)sB[0] + ldsbase);
    gload16(gB1, (char*)sB[0] + 8192 + ldsbase);
  }
  asm volatile("s_waitcnt vmcnt(0)" ::: "memory");
  __syncthreads();

  int cur = 0;
  for (int t = 0; t < nt; t++){
    if (t + 1 < nt){
      const int ke = (t + 1) << 6;
      gload16(gA0 + ke, (char*)sA[cur^1] + ldsbase);
      gload16(gA1 + ke, (char*)sA[cur^1] + 8192 + ldsbase);
      gload16(gB0 + ke, (char*)sB[cur^1] + ldsbase);
      gload16(gB1 + ke, (char*)sB[cur^1] + 8192 + ldsbase);
    }
    const __bf16* cA = sA[cur];
    const __bf16* cB = sB[cur];
    #pragma unroll
    for (int ks = 0; ks < 2; ks++){
      const int so = ((ks*4 + lk) ^ xr) * 8;
      bf16x8 af[4], bfr[2];
      #pragma unroll
      for (int i = 0; i < 4; i++) af[i]  = *(const bf16x8*)&cA[(wm + i*16 + li)*64 + so];
      #pragma unroll
      for (int j = 0; j < 2; j++) bfr[j] = *(const bf16x8*)&cB[(wn + j*16 + li)*64 + so];
      #pragma unroll
      for (int i = 0; i < 4; i++)
        #pragma unroll
        for (int j = 0; j < 2; j++) acc[i][j] = mfma16(af[i], bfr[j], acc[i][j]);
    }
    asm volatile("s_waitcnt vmcnt(0)" ::: "memory");
    __syncthreads();
    cur ^= 1;
  }

  #pragma unroll
  for (int i = 0; i < 4; i++){
    #pragma unroll
    for (int j = 0; j < 2; j++){
      int colg = n0 + wn + j*16 + li;
      float bc = b2f(bias[colg]);
      #pragma unroll
      for (int r2 = 0; r2 < 4; r2++){
        int rowg = m0 + wm + i*16 + lk*4 + r2;
        if (rowg < M){
          float vv = acc[i][j][r2] + bc;
          if (flags & 1) vv = gelu_t(vv);
          if (flags & 2) vv += res[(size_t)rowg * N + colg];
          if (flags & 4){
            size_t oidx = (size_t)(row_off + rowg) * N + colg;
            if (df == 0) ((float*)out)[oidx] = vv;
            else         ((bf*)out)[oidx]    = __float2bfloat16(vv);
          } else {
            ((bf*)out)[(size_t)rowg * N + colg] = __float2bfloat16(vv);
          }
        }
      }
    }
  }
}

// ------------------------------------------------------------------
// Relative-position bias tables per (window, head), TRANSPOSED layout:
// relT[blk] = { relHT[14][200], relWT[14][200] } with relHT[kh][grow],
// grow = qi+1. blk = w*12 + h, w chunk-local. Grid = nb*300.
__global__ __launch_bounds__(256) void bias_tables(const bf* __restrict__ qkv,
    const bf* __restrict__ rph, const bf* __restrict__ rpw, bf* __restrict__ relT){
  const int blk = blockIdx.x;
  const int w = blk / 12, h = blk % 12;
  const int tid = threadIdx.x, wv = tid >> 6, l = tid & 63;
  const int li = l & 15, lk = l >> 4;
  const bf* qbase = qkv + (size_t)w * 197 * 2304 + h * 64;
  bf* tbase = relT + (size_t)blk * 5600;
  for (int g = wv; g < 28; g += 4){
    bool isH = (g < 14);
    int pfix = isH ? g : (g - 14);
    int var  = li < 13 ? li : 13;
    int q = isH ? (1 + pfix*14 + var) : (1 + var*14 + pfix);
    f32x4 acc = {0.f,0.f,0.f,0.f};
    const bf* rp = isH ? rph : rpw;
    #pragma unroll
    for (int s = 0; s < 2; s++){
      bf16x8 a = *(const bf16x8*)(qbase + (size_t)q * 2304 + s*32 + lk*8);
      int idx = pfix + 13 - li;
      if (idx < 0) idx = 0;
      bf16x8 b = *(const bf16x8*)(rp + idx * 64 + s*32 + lk*8);
      acc = mfma16(a, b, acc);
    }
    #pragma unroll
    for (int r = 0; r < 4; r++){
      int mrow = lk*4 + r;
      int col = li;
      if (mrow <= 13 && col <= 13){
        int qi = isH ? (pfix*14 + mrow) : (mrow*14 + pfix);
        tbase[(isH ? 0 : 2800) + col*200 + qi + 1] = __float2bfloat16(acc[r]);
      }
    }
  }
}

// ------------------------------------------------------------------
// Attention per (window, head, q-half). Grid = nb*600, 4 waves.
__global__ __launch_bounds__(256) void attn_win(const bf* __restrict__ qkv,
    const bf* __restrict__ relT, bf* __restrict__ aout){
  __shared__ __bf16 Vt[64][232];     // V transposed [c][key], keys 0..223 (pad zero)
  __shared__ __bf16 Pl[4][16][232];  // per-wave P tile [qrow][key]
  const int blk = blockIdx.x;
  const int wh = blk >> 1, half = blk & 1;
  const int w = wh / 12, h = wh % 12;
  const int tid = threadIdx.x, wv = tid >> 6, l = tid & 63;
  const int li = l & 15, lk = l >> 4;
  const bf* qp = qkv + (size_t)w * 197 * 2304 + h * 64;
  const bf* kp = qp + 768;
  const bf* vp = qp + 1536;
  {
    const int cc = (tid & 7) * 8, rb = tid >> 3;
    #pragma unroll
    for (int pass = 0; pass < 7; pass++){
      int r = pass * 32 + rb;
      __bf16 vvv[8];
      if (r < 197){
        bf16x8 t = *(const bf16x8*)(vp + (size_t)r * 2304 + cc);
        #pragma unroll
        for (int e = 0; e < 8; e++) vvv[e] = t[e];
      } else {
        #pragma unroll
        for (int e = 0; e < 8; e++) vvv[e] = (__bf16)0.f;
      }
      #pragma unroll
      for (int e = 0; e < 8; e++) Vt[cc + e][r] = vvv[e];
    }
  }
  for (int i = l; i < 256; i += 64) Pl[wv][i >> 4][208 + (i & 15)] = (__bf16)0.f;
  __syncthreads();
  const bf* rHT = relT + (size_t)wh * 5600;
  const bf* rWT = rHT + 2800;
  const int qt0 = half * 7;
  const int nqt = half ? 6 : 7;
  for (int qt_l = wv; qt_l < nqt; qt_l += 4){
    const int qt = qt0 + qt_l;
    const int grow0 = qt*16 + lk*4;
    int qrow = qt * 16 + li; if (qrow > 196) qrow = 196;
    bf16x8 qa0 = *(const bf16x8*)(qp + (size_t)qrow * 2304 + lk*8);
    bf16x8 qa1 = *(const bf16x8*)(qp + (size_t)qrow * 2304 + 32 + lk*8);
    f32x4 sc[13];
    #pragma unroll
    for (int ct = 0; ct < 13; ct++){
      int kr = ct * 16 + li; if (kr > 196) kr = 196;
      bf16x8 kb0 = *(const bf16x8*)(kp + (size_t)kr * 2304 + lk*8);
      bf16x8 kb1 = *(const bf16x8*)(kp + (size_t)kr * 2304 + 32 + lk*8);
      f32x4 z = {0.f,0.f,0.f,0.f};
      z = mfma16(qa0, kb0, z);
      z = mfma16(qa1, kb1, z);
      sc[ct] = z;
    }
    float mx[4] = {-3e38f, -3e38f, -3e38f, -3e38f};
    #pragma unroll
    for (int ct = 0; ct < 13; ct++){
      const int col = ct * 16 + li;
      const int kiq = col >= 1 ? col - 1 : 0;
      const int kh = (kiq * 4682) >> 16;           // exact /14 for kiq<=206
      const int kw = kiq - kh * 14;
      const u16x4 rh4 = *(const u16x4*)(rHT + kh*200 + grow0);
      const u16x4 rw4 = *(const u16x4*)(rWT + kw*200 + grow0);
      #pragma unroll
      for (int r = 0; r < 4; r++){
        int grow = grow0 + r;
        float s = sc[ct][r] * 0.125f;      // SCALE = HD^-0.5
        if (col >= 197) s = -1e30f;
        else if (col >= 1 && grow >= 1 && grow < 197)
          s += bfbits(rh4[r]) + bfbits(rw4[r]);
        sc[ct][r] = s;
        mx[r] = fmaxf(mx[r], s);
      }
    }
    #pragma unroll
    for (int r = 0; r < 4; r++){
      #pragma unroll
      for (int off = 1; off < 16; off <<= 1) mx[r] = fmaxf(mx[r], __shfl_xor(mx[r], off));
    }
    float den[4] = {0.f,0.f,0.f,0.f};
    #pragma unroll
    for (int ct = 0; ct < 13; ct++)
      #pragma unroll
      for (int r = 0; r < 4; r++){
        float e = __expf(sc[ct][r] - mx[r]);
        sc[ct][r] = e; den[r] += e;
      }
    #pragma unroll
    for (int r = 0; r < 4; r++){
      #pragma unroll
      for (int off = 1; off < 16; off <<= 1) den[r] += __shfl_xor(den[r], off);
      den[r] = 1.f / den[r];
    }
    #pragma unroll
    for (int ct = 0; ct < 13; ct++)
      #pragma unroll
      for (int r = 0; r < 4; r++)
        Pl[wv][lk*4 + r][ct*16 + li] = (__bf16)(sc[ct][r] * den[r]);
    asm volatile("s_waitcnt lgkmcnt(0)" ::: "memory");
    __builtin_amdgcn_sched_barrier(0);
    #pragma unroll
    for (int n = 0; n < 4; n++){
      f32x4 o = {0.f,0.f,0.f,0.f};
      #pragma unroll
      for (int ks = 0; ks < 7; ks++){
        bf16x8 pa = *(const bf16x8*)&Pl[wv][li][ks*32 + lk*8];
        bf16x8 vb = *(const bf16x8*)&Vt[n*16 + li][ks*32 + lk*8];
        o = mfma16(pa, vb, o);
      }
      #pragma unroll
      for (int r = 0; r < 4; r++){
        int grow = qt * 16 + lk*4 + r;
        if (grow < 197)
          aout[((size_t)w * 197 + grow) * 768 + h*64 + n*16 + li] = __float2bfloat16(o[r]);
      }
    }
  }
}

// ------------------------------------------------------------------
// Un-window + cls-mean + residual for a chunk of nb batches (grid = nb*4097).
__global__ __launch_bounds__(256) void unwindow(const void* __restrict__ x, const void* __restrict__ cls,
    const bf* __restrict__ projoC, float* __restrict__ tok2, int b0, const int* flag){
  const int f = *flag;
  int tg = blockIdx.x;
  int bl = tg / 4097, t = tg % 4097;
  int batch = b0 + bl;
  const bf* projo = projoC + (size_t)bl * 4925 * 768;
  for (int c = threadIdx.x; c < 768; c += 256){
    float val, add;
    if (t == 0){
      val = ldx(cls, (size_t)batch * 768 + c, f);
      float s = 0.f;
      #pragma unroll
      for (int wi = 0; wi < 25; wi++)
        s += b2f(projo[((size_t)wi * 197) * 768 + c]);
      add = s * 0.04f;                  // 1/25
    } else {
      int idx = t - 1, gh = idx >> 6, gw = idx & 63;
      int wi = gh / 14, pi = gh % 14, wj = gw / 14, pj = gw % 14;
      int wwin = wi*5 + wj, tl = 1 + pi*14 + pj;
      val = ldx(x, ((size_t)batch * 4096 + idx) * 768 + c, f);
      add = b2f(projo[((size_t)wwin * 197 + tl) * 768 + c]);
    }
    tok2[((size_t)batch * 4097 + t) * 768 + c] = val + add;
  }
}

// ------------------------------------------------------------------
// Workspace layout — parametrized by nb (batches per chunk), chosen from ws_size:
//   [0,256) flag | [256,14,155,776) weights | [14,156,032..) small arrays
//   base0=14,188,800:
//     winx   [base0,            +nb*7,564,800)   (reused as attn_o)
//     qkvC   [.. ,              +nb*22,694,400)
//     projoC [.. ,              +nb*7,564,800)   (relT aliases its start, dead before proj)
//     tok2   [base0+nb*37,824,000, +50,343,936)  fp32, full
//   MLP phase (attn buffers dead): hbufC [base0, +nb*6,292,992), fc1gC after it.
//   ws_req(nb) = base0 + nb*37,824,000 + 50,343,936:
//     nb=1: 102.4MB (< proven 105.6) | nb=2: 140.2MB | nb=4: 215.9MB
extern "C" void kernel_launch(void* const* d_in, const int* in_sizes, int n_in,
                              void* d_out, int out_size, void* d_ws, size_t ws_size,
                              hipStream_t stream){
  (void)in_sizes; (void)n_in; (void)out_size;
  const void* x      = d_in[0];
  const void* cls    = d_in[1];
  const void* qkv_w  = d_in[2];
  const void* qkv_bv = d_in[3];
  const void* proj_w = d_in[4];
  const void* proj_bv= d_in[5];
  const void* rph    = d_in[6];
  const void* rpw    = d_in[7];
  const void* n1s    = d_in[8];
  const void* n1b    = d_in[9];
  const void* n2s    = d_in[10];
  const void* n2b    = d_in[11];
  const void* fc1_w  = d_in[12];
  const void* fc1_bv = d_in[13];
  const void* fc2_w  = d_in[14];
  const void* fc2_bv = d_in[15];

  char* ws = (char*)d_ws;
  int* flagp  = (int*)(ws + 0);
  bf* wt_qkv  = (bf*)(ws + 256);
  bf* wt_proj = (bf*)(ws + 3539200);
  bf* wt_fc1  = (bf*)(ws + 4718848);
  bf* wt_fc2  = (bf*)(ws + 9437440);
  bf* c_qkv_b = (bf*)(ws + 14156032);
  bf* c_proj_b= (bf*)(ws + 14160640);
  bf* c_fc1_b = (bf*)(ws + 14162176);
  bf* c_fc2_b = (bf*)(ws + 14168320);
  bf* c_n1s   = (bf*)(ws + 14169856);
  bf* c_n1b   = (bf*)(ws + 14171392);
  bf* c_n2s   = (bf*)(ws + 14172928);
  bf* c_n2b   = (bf*)(ws + 14174464);
  bf* c_rph   = (bf*)(ws + 14176000);
  bf* c_rpw   = (bf*)(ws + 14179456);

  const size_t base0 = 14188800;
  int nb = 1;
  if      (ws_size >= base0 + 4ull*37824000 + 50343936) nb = 4;
  else if (ws_size >= base0 + 2ull*37824000 + 50343936) nb = 2;
  const size_t o_winx  = base0;
  const size_t o_qkv   = o_winx + (size_t)nb * 7564800;
  const size_t o_projo = o_qkv  + (size_t)nb * 22694400;
  const size_t o_tok2  = o_projo+ (size_t)nb * 7564800;
  const size_t o_fc1g  = base0  + (size_t)nb * 6292992;

  bf* winx_c  = (bf*)(ws + o_winx);
  bf* attn_oC = winx_c;                 // reuse (winx dead after qkv gemm)
  bf* qkvC    = (bf*)(ws + o_qkv);
  bf* projoC  = (bf*)(ws + o_projo);
  bf* relT    = (bf*)(ws + o_projo);    // alias: nb*3.36MB, dead before proj gemm
  float* tok2 = (float*)(ws + o_tok2);
  bf* hbufC   = (bf*)(ws + base0);      // MLP phase (attn buffers dead)
  bf* fc1gC   = (bf*)(ws + o_fc1g);

  detect_dtype<<<1, 1, 0, stream>>>(n1s, flagp);

  conv_bf16<<<9,  256, 0, stream>>>(qkv_bv,  c_qkv_b, 2304, flagp);
  conv_bf16<<<3,  256, 0, stream>>>(proj_bv, c_proj_b, 768, flagp);
  conv_bf16<<<12, 256, 0, stream>>>(fc1_bv,  c_fc1_b, 3072, flagp);
  conv_bf16<<<3,  256, 0, stream>>>(fc2_bv,  c_fc2_b,  768, flagp);
  conv_bf16<<<3,  256, 0, stream>>>(n1s, c_n1s, 768, flagp);
  conv_bf16<<<3,  256, 0, stream>>>(n1b, c_n1b, 768, flagp);
  conv_bf16<<<3,  256, 0, stream>>>(n2s, c_n2s, 768, flagp);
  conv_bf16<<<3,  256, 0, stream>>>(n2b, c_n2b, 768, flagp);
  conv_bf16<<<7,  256, 0, stream>>>(rph, c_rph, 1728, flagp);
  conv_bf16<<<7,  256, 0, stream>>>(rpw, c_rpw, 1728, flagp);

  transpose_w<<<dim3(72, 24), 256, 0, stream>>>(qkv_w, wt_qkv, 768, 2304, flagp);
  transpose_w<<<dim3(24, 24), 256, 0, stream>>>(proj_w, wt_proj, 768, 768, flagp);
  transpose_w<<<dim3(96, 24), 256, 0, stream>>>(fc1_w, wt_fc1, 768, 3072, flagp);
  transpose_w<<<dim3(24, 96), 256, 0, stream>>>(fc2_w, wt_fc2, 3072, 768, flagp);

  const int nchunk = 4 / nb;
  for (int ci = 0; ci < nchunk; ci++){
    const int b0 = ci * nb;
    const int Mq = nb * 4925;
    const int gy = (Mq + 127) / 128;
    ln_window<<<nb*4925, 256, 0, stream>>>(x, cls, c_n1s, c_n1b, winx_c, b0, flagp);
    gemm128<<<dim3(18, gy), 512, 0, stream>>>(winx_c, wt_qkv, c_qkv_b, nullptr, qkvC,
                                              Mq, 2304, 768, 0, flagp, 0);
    bias_tables<<<nb*300, 256, 0, stream>>>(qkvC, c_rph, c_rpw, relT);
    attn_win<<<nb*600, 256, 0, stream>>>(qkvC, relT, attn_oC);
    gemm128<<<dim3(6, gy), 512, 0, stream>>>(attn_oC, wt_proj, c_proj_b, nullptr, projoC,
                                             Mq, 768, 768, 0, flagp, 0);
    unwindow<<<nb*4097, 256, 0, stream>>>(x, cls, projoC, tok2, b0, flagp);
  }

  for (int ci = 0; ci < nchunk; ci++){
    const int b0 = ci * nb;
    const int Mm = nb * 4097;
    const int gym = (Mm + 127) / 128;
    ln_f32<<<Mm, 256, 0, stream>>>(tok2 + (size_t)b0 * 4097 * 768, c_n2s, c_n2b, hbufC);
    gemm128<<<dim3(24, gym), 512, 0, stream>>>(hbufC, wt_fc1, c_fc1_b, nullptr, fc1gC,
                                               Mm, 3072, 768, 1, flagp, 0);
    gemm128<<<dim3(6, gym), 512, 0, stream>>>(fc1gC, wt_fc2, c_fc2_b,
                                              tok2 + (size_t)b0 * 4097 * 768,
                                              d_out,
                                              Mm, 768, 3072, 2 | 4, flagp, b0 * 4097);
  }
}